// Round 5
// baseline (641.182 us; speedup 1.0000x reference)
//
#include <hip/hip_runtime.h>
#include <hip/hip_bf16.h>
#include <stdint.h>

#define IN_DIM 384
#define HID 64
#define C1 256   // 4 heads * 64
#define C2 128   // 2 heads * 64

typedef unsigned int uint32;
typedef __bf16 bf16x8 __attribute__((ext_vector_type(8)));
typedef float f32x4 __attribute__((ext_vector_type(4)));

static __device__ __forceinline__ float bf2f(unsigned short u){
    return __uint_as_float(((uint32)u) << 16);
}
static __device__ __forceinline__ unsigned short f2bf(float x){
    uint32 u = __float_as_uint(x);
    return (unsigned short)((u + 0x7FFFu + ((u >> 16) & 1u)) >> 16);
}
static __device__ __forceinline__ uint32 pack2(float a, float b){
    return (uint32)f2bf(a) | ((uint32)f2bf(b) << 16);
}

// ---------------- CSR build ----------------
__global__ void k_zero(int* deg, int* cur, int N){
    int i = blockIdx.x*256 + threadIdx.x;
    if (i < N){ deg[i] = 0; cur[i] = 0; }
}
__global__ void k_hist(const int* __restrict__ ei, int* deg, int E){
    int i = blockIdx.x*256 + threadIdx.x;
    if (i < E) atomicAdd(&deg[ei[E + i]], 1);
}
__global__ void k_scan1(const int* __restrict__ deg, int* rowptr, int* part, int N){
    __shared__ int s[256];
    int tid = threadIdx.x;
    int i = blockIdx.x*256 + tid;
    int v = (i < N) ? deg[i] : 0;
    s[tid] = v; __syncthreads();
    for (int off = 1; off < 256; off <<= 1){
        int t = (tid >= off) ? s[tid - off] : 0;
        __syncthreads();
        s[tid] += t;
        __syncthreads();
    }
    if (i < N) rowptr[i] = s[tid] - v;
    if (tid == 255) part[blockIdx.x] = s[tid];
}
__global__ void k_scan2(int* part, int nb){
    __shared__ int s[512];
    int tid = threadIdx.x;
    int v = (tid < nb) ? part[tid] : 0;
    s[tid] = v; __syncthreads();
    for (int off = 1; off < 512; off <<= 1){
        int t = (tid >= off) ? s[tid - off] : 0;
        __syncthreads();
        s[tid] += t;
        __syncthreads();
    }
    if (tid < nb) part[tid] = s[tid] - v;
}
__global__ void k_scan3(int* rowptr, const int* __restrict__ part, int N, int E){
    int i = blockIdx.x*256 + threadIdx.x;
    if (i < N) rowptr[i] += part[blockIdx.x];
    if (i == 0) rowptr[N] = E;
}
__global__ void k_scatter(const int* __restrict__ ei, const int* __restrict__ rowptr,
                          int* cur, int* colx, int* dstx, int E){
    int i = blockIdx.x*256 + threadIdx.x;
    if (i < E){
        int d = ei[E + i];
        int pos = atomicAdd(&cur[d], 1);
        int p = rowptr[d] + pos;
        colx[p] = ei[i];
        dstx[p] = d;
    }
}

// ---------------- weight pre-swizzle: contiguous-k fragment order ----------------
__global__ __launch_bounds__(256) void k_cvtW(const float* __restrict__ W,
        unsigned short* __restrict__ Wf, int ncol, int ntiles, int nunits){
    int unit = blockIdx.x*4 + (threadIdx.x >> 6);
    if (unit >= nunits) return;
    int l = threadIdx.x & 63;
    int s = unit / ntiles, ct = unit % ntiles;
    int col = ct*16 + (l & 15);
    int g = l >> 4;
    unsigned short o[8];
    #pragma unroll
    for (int j = 0; j < 8; j++){
        int k = s*32 + g*8 + j;
        o[j] = f2bf(W[(size_t)k*ncol + col]);
    }
    ushort4* dst = (ushort4*)&Wf[((size_t)unit*64 + l)*8];
    dst[0] = make_ushort4(o[0], o[1], o[2], o[3]);
    dst[1] = make_ushort4(o[4], o[5], o[6], o[7]);
}

// ---------------- constant precompute: pad bias, emotion gate, aw1 transpose --------
__global__ __launch_bounds__(256) void k_prep(const float* __restrict__ W1,
        const float* __restrict__ pad, const float* __restrict__ gw, const float* __restrict__ gb,
        const float* __restrict__ aw1,
        float* __restrict__ c1v, float* __restrict__ gate, float* __restrict__ aw1t){
    int tid = threadIdx.x;
    c1v[tid] = pad[0]*W1[(size_t)(IN_DIM+0)*C1 + tid]
             + pad[1]*W1[(size_t)(IN_DIM+1)*C1 + tid]
             + pad[2]*W1[(size_t)(IN_DIM+2)*C1 + tid];
    if (tid < HID){
        float g = pad[0]*gw[0*HID + tid] + pad[1]*gw[1*HID + tid] + pad[2]*gw[2*HID + tid] + gb[tid];
        gate[tid] = 1.f/(1.f + __expf(-g));
    }
    for (int i = tid; i < C2*HID; i += 256){
        int c = i >> 6, l = i & 63;
        aw1t[l*C2 + c] = aw1[i];
    }
}

// ---------------- GEMM1 (MFMA): h1 = [x|pad]@W1 + fused al1 epilogue ----------------
__global__ __launch_bounds__(256) void k_gemm1_mfma(const float* __restrict__ x,
        const unsigned short* __restrict__ Wf, const float* __restrict__ c1v,
        const float* __restrict__ as1, const float* __restrict__ ad1,
        unsigned short* __restrict__ h1, float* __restrict__ als, float* __restrict__ ald, int N)
{
    __shared__ unsigned short Af[2][8*64*8];   // 2 x 8KB
    const int tid = threadIdx.x;
    const int l   = tid & 63;
    const int w   = tid >> 6;
    const int n0  = blockIdx.x * 128;

    const int srow = tid & 127;
    const int jh   = tid >> 7;
    const int srt  = srow >> 4, srr = srow & 15;
    const int d0   = (srt*64 + (jh*2+0)*16 + srr)*8;
    const int d1   = (srt*64 + (jh*2+1)*16 + srr)*8;
    int crow = n0 + srow; if (crow > N-1) crow = N-1;
    const float* xrow = x + (size_t)crow*IN_DIM + jh*16;

    f32x4 acc[4][8];
    #pragma unroll
    for (int i = 0; i < 4; i++)
        #pragma unroll
        for (int rt = 0; rt < 8; rt++)
            acc[i][rt] = (f32x4){0.f, 0.f, 0.f, 0.f};

    float4 ra, rb, rc, rd;
    uint4 wcur[4], wnxt[4];

    ra = *(const float4*)(xrow + 0); rb = *(const float4*)(xrow + 4);
    rc = *(const float4*)(xrow + 8); rd = *(const float4*)(xrow + 12);
    {
        uint4 u0, u1;
        u0.x = pack2(ra.x, ra.y); u0.y = pack2(ra.z, ra.w);
        u0.z = pack2(rb.x, rb.y); u0.w = pack2(rb.z, rb.w);
        u1.x = pack2(rc.x, rc.y); u1.y = pack2(rc.z, rc.w);
        u1.z = pack2(rd.x, rd.y); u1.w = pack2(rd.z, rd.w);
        *(uint4*)&Af[0][d0] = u0;
        *(uint4*)&Af[0][d1] = u1;
    }
    {
        const unsigned short* p = Wf + ((size_t)(w*4)*64 + l)*8;
        #pragma unroll
        for (int i = 0; i < 4; i++) wcur[i] = *(const uint4*)(p + (size_t)i*512);
    }
    __syncthreads();

    for (int s = 0; s < 12; ++s){
        if (s < 11){
            const float* src = xrow + (s+1)*32;
            ra = *(const float4*)(src + 0); rb = *(const float4*)(src + 4);
            rc = *(const float4*)(src + 8); rd = *(const float4*)(src + 12);
            const unsigned short* p = Wf + ((size_t)((s+1)*16 + w*4)*64 + l)*8;
            #pragma unroll
            for (int i = 0; i < 4; i++) wnxt[i] = *(const uint4*)(p + (size_t)i*512);
        }
        bf16x8 af[8];
        #pragma unroll
        for (int rt = 0; rt < 8; rt++)
            af[rt] = __builtin_bit_cast(bf16x8, *(const uint4*)&Af[s&1][(rt*64 + l)*8]);
        #pragma unroll
        for (int i = 0; i < 4; i++){
            bf16x8 bw = __builtin_bit_cast(bf16x8, wcur[i]);
            #pragma unroll
            for (int rt = 0; rt < 8; rt++)
                acc[i][rt] = __builtin_amdgcn_mfma_f32_16x16x32_bf16(bw, af[rt], acc[i][rt], 0, 0, 0);
        }
        if (s < 11){
            uint4 u0, u1;
            u0.x = pack2(ra.x, ra.y); u0.y = pack2(ra.z, ra.w);
            u0.z = pack2(rb.x, rb.y); u0.w = pack2(rb.z, rb.w);
            u1.x = pack2(rc.x, rc.y); u1.y = pack2(rc.z, rc.w);
            u1.z = pack2(rd.x, rd.y); u1.w = pack2(rd.z, rd.w);
            *(uint4*)&Af[(s+1)&1][d0] = u0;
            *(uint4*)&Af[(s+1)&1][d1] = u1;
            __syncthreads();
            #pragma unroll
            for (int i = 0; i < 4; i++) wcur[i] = wnxt[i];
        }
    }

    const int g = l >> 4;
    float4 cvv[4], av[4], dv[4];
    #pragma unroll
    for (int i = 0; i < 4; i++){
        int cl = i*16 + g*4;
        cvv[i] = *(const float4*)&c1v[w*64 + cl];
        av[i]  = *(const float4*)&as1[w*64 + cl];
        dv[i]  = *(const float4*)&ad1[w*64 + cl];
    }
    #pragma unroll
    for (int rt = 0; rt < 8; rt++){
        int node = n0 + rt*16 + (l & 15);
        bool ok = node < N;
        float ps = 0.f, pd = 0.f;
        #pragma unroll
        for (int i = 0; i < 4; i++){
            float h0 = acc[i][rt][0] + cvv[i].x;
            float h1v = acc[i][rt][1] + cvv[i].y;
            float h2v = acc[i][rt][2] + cvv[i].z;
            float h3v = acc[i][rt][3] + cvv[i].w;
            ps += h0*av[i].x + h1v*av[i].y + h2v*av[i].z + h3v*av[i].w;
            pd += h0*dv[i].x + h1v*dv[i].y + h2v*dv[i].z + h3v*dv[i].w;
            if (ok){
                ushort4 o = make_ushort4(f2bf(h0), f2bf(h1v), f2bf(h2v), f2bf(h3v));
                *(ushort4*)&h1[(size_t)node*C1 + w*64 + i*16 + g*4] = o;
            }
        }
        ps += __shfl_xor(ps, 16, 64); ps += __shfl_xor(ps, 32, 64);
        pd += __shfl_xor(pd, 16, 64); pd += __shfl_xor(pd, 32, 64);
        if (ok && g == 0){
            als[(size_t)node*4 + w] = ps;
            ald[(size_t)node*4 + w] = pd;
        }
    }
}

// ---------------- GEMM2 (MFMA): h2 = x2 @ W2 + fused al2 epilogue ----------------
__global__ __launch_bounds__(256) void k_gemm2_mfma(const unsigned short* __restrict__ x2,
        const unsigned short* __restrict__ Wf,
        const float* __restrict__ as2, const float* __restrict__ ad2,
        unsigned short* __restrict__ h2, float* __restrict__ als, float* __restrict__ ald, int N)
{
    __shared__ unsigned short Af[2][8*64*8];
    const int tid = threadIdx.x;
    const int l   = tid & 63;
    const int w   = tid >> 6;
    const int wr  = w >> 1, wc = w & 1;
    const int n0  = blockIdx.x * 128;

    const int srow = tid >> 1;
    const int half = tid & 1;
    const int srt  = srow >> 4, srr = srow & 15;
    const int d0   = (srt*64 + (half*2+0)*16 + srr)*8;
    const int d1   = d0 + 128;
    int crow = n0 + srow; if (crow > N-1) crow = N-1;
    const unsigned short* xrow = x2 + (size_t)crow*C1 + half*16;

    f32x4 acc[4][4];
    #pragma unroll
    for (int i = 0; i < 4; i++)
        #pragma unroll
        for (int rt = 0; rt < 4; rt++)
            acc[i][rt] = (f32x4){0.f, 0.f, 0.f, 0.f};

    uint4 p0, p1, wcur[4], wnxt[4];
    p0 = *(const uint4*)(xrow + 0);
    p1 = *(const uint4*)(xrow + 8);
    *(uint4*)&Af[0][d0] = p0;
    *(uint4*)&Af[0][d1] = p1;
    {
        const unsigned short* p = Wf + ((size_t)(wc*4)*64 + l)*8;
        #pragma unroll
        for (int i = 0; i < 4; i++) wcur[i] = *(const uint4*)(p + (size_t)i*512);
    }
    __syncthreads();

    for (int s = 0; s < 8; ++s){
        if (s < 7){
            p0 = *(const uint4*)(xrow + (s+1)*32);
            p1 = *(const uint4*)(xrow + (s+1)*32 + 8);
            const unsigned short* p = Wf + ((size_t)((s+1)*8 + wc*4)*64 + l)*8;
            #pragma unroll
            for (int i = 0; i < 4; i++) wnxt[i] = *(const uint4*)(p + (size_t)i*512);
        }
        bf16x8 af[4];
        #pragma unroll
        for (int rt = 0; rt < 4; rt++)
            af[rt] = __builtin_bit_cast(bf16x8, *(const uint4*)&Af[s&1][((wr*4 + rt)*64 + l)*8]);
        #pragma unroll
        for (int i = 0; i < 4; i++){
            bf16x8 bw = __builtin_bit_cast(bf16x8, wcur[i]);
            #pragma unroll
            for (int rt = 0; rt < 4; rt++)
                acc[i][rt] = __builtin_amdgcn_mfma_f32_16x16x32_bf16(bw, af[rt], acc[i][rt], 0, 0, 0);
        }
        if (s < 7){
            *(uint4*)&Af[(s+1)&1][d0] = p0;
            *(uint4*)&Af[(s+1)&1][d1] = p1;
            __syncthreads();
            #pragma unroll
            for (int i = 0; i < 4; i++) wcur[i] = wnxt[i];
        }
    }

    const int g = l >> 4;
    float4 av[4], dv[4];
    #pragma unroll
    for (int i = 0; i < 4; i++){
        int cl = i*16 + g*4;
        av[i] = *(const float4*)&as2[wc*64 + cl];
        dv[i] = *(const float4*)&ad2[wc*64 + cl];
    }
    #pragma unroll
    for (int rt = 0; rt < 4; rt++){
        int node = n0 + wr*64 + rt*16 + (l & 15);
        bool ok = node < N;
        float ps = 0.f, pd = 0.f;
        #pragma unroll
        for (int i = 0; i < 4; i++){
            float h0 = acc[i][rt][0], h1v = acc[i][rt][1];
            float h2v = acc[i][rt][2], h3v = acc[i][rt][3];
            ps += h0*av[i].x + h1v*av[i].y + h2v*av[i].z + h3v*av[i].w;
            pd += h0*dv[i].x + h1v*dv[i].y + h2v*dv[i].z + h3v*dv[i].w;
            if (ok){
                ushort4 o = make_ushort4(f2bf(h0), f2bf(h1v), f2bf(h2v), f2bf(h3v));
                *(ushort4*)&h2[(size_t)node*C2 + wc*64 + i*16 + g*4] = o;
            }
        }
        ps += __shfl_xor(ps, 16, 64); ps += __shfl_xor(ps, 32, 64);
        pd += __shfl_xor(pd, 16, 64); pd += __shfl_xor(pd, 32, 64);
        if (ok && g == 0){
            als[(size_t)node*2 + wc] = ps;
            ald[(size_t)node*2 + wc] = pd;
        }
    }
}

// ---------------- A: edge-parallel logits e = leaky(als[src]+ald[dst]) ----------------
template<int H>
__global__ __launch_bounds__(256) void k_elogit(const int* __restrict__ colx,
        const int* __restrict__ dstx, const float* __restrict__ als,
        const float* __restrict__ ald, float* __restrict__ ep, int E)
{
    int i = blockIdx.x*256 + threadIdx.x;
    if (i >= E) return;
    int s = colx[i], d = dstx[i];
    if constexpr (H == 4){
        float4 a = *(const float4*)&als[(size_t)s*4];
        float4 b = *(const float4*)&ald[(size_t)d*4];
        float4 e;
        e.x = a.x + b.x; e.x = fmaxf(e.x, 0.2f*e.x);
        e.y = a.y + b.y; e.y = fmaxf(e.y, 0.2f*e.y);
        e.z = a.z + b.z; e.z = fmaxf(e.z, 0.2f*e.z);
        e.w = a.w + b.w; e.w = fmaxf(e.w, 0.2f*e.w);
        *(float4*)&ep[(size_t)i*4] = e;
    } else {
        float2 a = *(const float2*)&als[(size_t)s*2];
        float2 b = *(const float2*)&ald[(size_t)d*2];
        float2 e;
        e.x = a.x + b.x; e.x = fmaxf(e.x, 0.2f*e.x);
        e.y = a.y + b.y; e.y = fmaxf(e.y, 0.2f*e.y);
        *(float2*)&ep[(size_t)i*2] = e;
    }
}

// ---------------- B: thread per (node,head) segment softmax; ep <- p (in place) -------
template<int H>
__global__ __launch_bounds__(256) void k_segsm(const int* __restrict__ rowptr,
        const float* __restrict__ als, const float* __restrict__ ald,
        float* __restrict__ ep, float* __restrict__ den, float* __restrict__ pSelf, int NH)
{
    int t = blockIdx.x*256 + threadIdx.x;
    if (t >= NH) return;
    int node = t / H;
    int head = t - node*H;
    int base = rowptr[node];
    int cnt  = rowptr[node+1] - base;
    float es = als[t] + ald[t];
    es = fmaxf(es, 0.2f*es);
    float m = es;
    for (int j = 0; j < cnt; j++)
        m = fmaxf(m, ep[(size_t)(base + j)*H + head]);
    float ps = __expf(es - m);
    float dn = ps;
    for (int j = 0; j < cnt; j++){
        size_t idx = (size_t)(base + j)*H + head;
        float p = __expf(ep[idx] - m);
        ep[idx] = p;
        dn += p;
    }
    den[t]   = dn;
    pSelf[t] = ps;
}

// ---------------- C: wave-per-node weighted gather-sum (no softmax in loop) ----------
template<int H, int CPL, int LAYER>
__global__ __launch_bounds__(256) void k_gat(const unsigned short* __restrict__ hlin,
        const float* __restrict__ ep, const float* __restrict__ den, const float* __restrict__ pSelf,
        const int* __restrict__ rowptr, const int* __restrict__ colx,
        const float* __restrict__ bias,
        const float* __restrict__ gate, const float* __restrict__ aw1t,
        const float* __restrict__ ab1, const float* __restrict__ aw2, const float* __restrict__ ab2,
        unsigned short* __restrict__ out_bf, float* __restrict__ out_f,
        float* __restrict__ attn, int N)
{
    constexpr int C = H*64;
    constexpr uint32 RB = C*2;               // bf16 row bytes
    __shared__ float hs[4][C2];
    int lane = threadIdx.x & 63, wid = threadIdx.x >> 6;
    int n = blockIdx.x*4 + wid;
    if (n >= N) return;
    const int c0 = lane*CPL;
    const int head = c0 >> 6;
    const int base = rowptr[n];
    const int cnt  = rowptr[n+1] - base;
    const char* hbase = (const char*)hlin + (uint32)c0*2;

    float acc[CPL];
    {
        float psf = pSelf[(uint32)n*H + head];
        if constexpr (CPL == 4){
            ushort4 v = *(const ushort4*)(hbase + (size_t)(uint32)n*RB);
            acc[0] = psf*bf2f(v.x); acc[1] = psf*bf2f(v.y);
            acc[2] = psf*bf2f(v.z); acc[3] = psf*bf2f(v.w);
        } else {
            uint32 v = *(const uint32*)(hbase + (size_t)(uint32)n*RB);
            acc[0] = psf*bf2f((unsigned short)(v & 0xffff));
            acc[1] = psf*bf2f((unsigned short)(v >> 16));
        }
    }
    for (int i = 0; i < cnt; i += 4){
        int idx[4], sk[4];
        #pragma unroll
        for (int k = 0; k < 4; k++){
            int ii = i + k; if (ii > cnt-1) ii = cnt-1;
            idx[k] = base + ii;
        }
        #pragma unroll
        for (int k = 0; k < 4; k++) sk[k] = colx[idx[k]];
        float pk[4];
        #pragma unroll
        for (int k = 0; k < 4; k++){
            float pv = ep[(size_t)(uint32)idx[k]*H + head];   // position-indexed: no colx dep
            pk[k] = (i + k < cnt) ? pv : 0.f;
        }
        if constexpr (CPL == 4){
            ushort4 h4[4];
            #pragma unroll
            for (int k = 0; k < 4; k++) h4[k] = *(const ushort4*)(hbase + (size_t)(uint32)sk[k]*RB);
            #pragma unroll
            for (int k = 0; k < 4; k++){
                acc[0] += pk[k]*bf2f(h4[k].x);
                acc[1] += pk[k]*bf2f(h4[k].y);
                acc[2] += pk[k]*bf2f(h4[k].z);
                acc[3] += pk[k]*bf2f(h4[k].w);
            }
        } else {
            uint32 h2v[4];
            #pragma unroll
            for (int k = 0; k < 4; k++) h2v[k] = *(const uint32*)(hbase + (size_t)(uint32)sk[k]*RB);
            #pragma unroll
            for (int k = 0; k < 4; k++){
                acc[0] += pk[k]*bf2f((unsigned short)(h2v[k] & 0xffff));
                acc[1] += pk[k]*bf2f((unsigned short)(h2v[k] >> 16));
            }
        }
    }

    float inv = 1.f/(den[(uint32)n*H + head] + 1e-16f);
    if constexpr (LAYER == 1){
        unsigned short o[CPL];
        #pragma unroll
        for (int j = 0; j < CPL; j++){
            float r = acc[j]*inv + bias[c0 + j];
            r = (r > 0.f) ? r : (__expf(r) - 1.f);   // elu
            o[j] = f2bf(r);
        }
        if constexpr (CPL == 4){
            ushort4 ov; ov.x = o[0]; ov.y = o[1]; ov.z = o[2]; ov.w = o[3];
            *(ushort4*)&out_bf[(size_t)n*C + c0] = ov;
        }
    } else {
        #pragma unroll
        for (int j = 0; j < CPL; j++){
            float r = acc[j]*inv + bias[c0 + j];
            r = (r > 0.f) ? r : (__expf(r) - 1.f);   // elu
            float o = r*gate[(c0 + j) & 63];
            out_f[(size_t)n*C + c0 + j] = o;
            hs[wid][c0 + j] = o;
        }
        // fused attention-score MLP (wave-local; aw1 pre-transposed to [64][128])
        float a = ab1[lane];
        const float* awrow = aw1t + lane*C2;
        #pragma unroll 8
        for (int c = 0; c < C2; c += 4){
            float4 hv4 = *(const float4*)&hs[wid][c];
            float4 w4  = *(const float4*)&awrow[c];
            a += hv4.x*w4.x + hv4.y*w4.y + hv4.z*w4.z + hv4.w*w4.w;
        }
        a = fmaxf(a, 0.f);
        float part = a*aw2[lane];
        #pragma unroll
        for (int mm = 32; mm >= 1; mm >>= 1) part += __shfl_xor(part, mm, 64);
        if (lane == 0) attn[n] = 1.f/(1.f + __expf(-(part + ab2[0])));
    }
}

extern "C" void kernel_launch(void* const* d_in, const int* in_sizes, int n_in,
                              void* d_out, int out_size, void* d_ws, size_t ws_size,
                              hipStream_t stream)
{
    const float* x    = (const float*)d_in[0];
    const int*   ei   = (const int*)  d_in[1];
    const float* pad  = (const float*)d_in[2];
    const float* W1   = (const float*)d_in[3];
    const float* as1  = (const float*)d_in[4];
    const float* ad1  = (const float*)d_in[5];
    const float* b1   = (const float*)d_in[6];
    const float* W2   = (const float*)d_in[7];
    const float* as2  = (const float*)d_in[8];
    const float* ad2  = (const float*)d_in[9];
    const float* b2   = (const float*)d_in[10];
    const float* aw1  = (const float*)d_in[11];
    const float* ab1  = (const float*)d_in[12];
    const float* aw2  = (const float*)d_in[13];
    const float* ab2  = (const float*)d_in[14];
    const float* gw   = (const float*)d_in[15];
    const float* gb   = (const float*)d_in[16];

    const int N = in_sizes[0] / IN_DIM;
    const int E = in_sizes[1] / 2;

    float* outh    = (float*)d_out;
    float* outattn = outh + (size_t)N*C2;

    char* w = (char*)d_ws;
    auto alloc = [&](size_t bytes)->char*{
        char* p = w;
        w += (bytes + 255) & ~(size_t)255;
        return p;
    };
    unsigned short* h1  = (unsigned short*)alloc((size_t)N*C1*2);
    unsigned short* x2  = (unsigned short*)alloc((size_t)N*C1*2);
    unsigned short* h2  = (unsigned short*)alloc((size_t)N*C2*2);
    float* als1 = (float*)alloc((size_t)N*4*4);
    float* ald1 = (float*)alloc((size_t)N*4*4);
    float* als2 = (float*)alloc((size_t)N*2*4);
    float* ald2 = (float*)alloc((size_t)N*2*4);
    int* deg    = (int*)alloc((size_t)N*4);
    int* cur    = (int*)alloc((size_t)N*4);
    int* rowptr = (int*)alloc((size_t)(N+1)*4);
    int* colx   = (int*)alloc((size_t)E*4);
    int* dstx   = (int*)alloc((size_t)E*4);
    int* part   = (int*)alloc(512*4);
    unsigned short* Wf1 = (unsigned short*)alloc((size_t)12*16*64*8*2);
    unsigned short* Wf2 = (unsigned short*)alloc((size_t)8*8*64*8*2);
    float* c1v  = (float*)alloc(C1*4);
    float* gate = (float*)alloc(HID*4);
    float* aw1t = (float*)alloc((size_t)C2*HID*4);

    // Lifetime-based aliases (no new footprint):
    // layer-1 softmax scratch lives in the (not yet written) h2 buffer.
    float* ep1    = (float*)h2;                                   // E*4 floats
    float* den1   = (float*)((char*)h2 + (size_t)E*16);           // N*4 floats
    float* pSelf1 = (float*)((char*)h2 + (size_t)E*16 + (size_t)N*16);
    // layer-2 softmax scratch lives in x2 (dead after gemm2 reads it).
    float* ep2    = (float*)x2;                                   // E*2 floats
    float* den2   = (float*)((char*)x2 + (size_t)E*8);            // N*2 floats
    float* pSelf2 = (float*)((char*)x2 + (size_t)E*8 + (size_t)N*8);

    const int nbN = (N + 255)/256;
    const int nbE = (E + 255)/256;
    const int nbW = (N + 3)/4;        // wave-per-node kernels
    const int nbG = (N + 127)/128;    // gemm row blocks

    // weight swizzles + constants (independent of CSR)
    k_cvtW <<<(192+3)/4, 256, 0, stream>>>(W1, Wf1, C1, 16, 192);
    k_cvtW <<<(64+3)/4,  256, 0, stream>>>(W2, Wf2, C2, 8, 64);
    k_prep <<<1, 256, 0, stream>>>(W1, pad, gw, gb, aw1, c1v, gate, aw1t);

    // CSR by destination
    k_zero   <<<nbN, 256, 0, stream>>>(deg, cur, N);
    k_hist   <<<nbE, 256, 0, stream>>>(ei, deg, E);
    k_scan1  <<<nbN, 256, 0, stream>>>(deg, rowptr, part, N);
    k_scan2  <<<1, 512, 0, stream>>>(part, nbN);
    k_scan3  <<<nbN, 256, 0, stream>>>(rowptr, part, N, E);
    k_scatter<<<nbE, 256, 0, stream>>>(ei, rowptr, cur, colx, dstx, E);

    // ---- layer 1 ----
    k_gemm1_mfma<<<nbG, 256, 0, stream>>>(x, Wf1, c1v, as1, ad1, h1, als1, ald1, N);
    k_elogit<4><<<nbE, 256, 0, stream>>>(colx, dstx, als1, ald1, ep1, E);
    k_segsm<4> <<<(N*4 + 255)/256, 256, 0, stream>>>(rowptr, als1, ald1, ep1, den1, pSelf1, N*4);
    k_gat<4,4,1><<<nbW, 256, 0, stream>>>(h1, ep1, den1, pSelf1, rowptr, colx, b1,
                                          nullptr, nullptr, nullptr, nullptr, nullptr,
                                          x2, nullptr, nullptr, N);

    // ---- layer 2 ----
    k_gemm2_mfma<<<nbG, 256, 0, stream>>>(x2, Wf2, as2, ad2, h2, als2, ald2, N);
    k_elogit<2><<<nbE, 256, 0, stream>>>(colx, dstx, als2, ald2, ep2, E);
    k_segsm<2> <<<(N*2 + 255)/256, 256, 0, stream>>>(rowptr, als2, ald2, ep2, den2, pSelf2, N*2);
    k_gat<2,2,2><<<nbW, 256, 0, stream>>>(h2, ep2, den2, pSelf2, rowptr, colx, b2,
                                          gate, aw1t, ab1, aw2, ab2,
                                          nullptr, outh, outattn, N);
}

// Round 6
// 396.880 us; speedup vs baseline: 1.6156x; 1.6156x over previous
//
#include <hip/hip_runtime.h>
#include <hip/hip_bf16.h>
#include <stdint.h>

#define IN_DIM 384
#define HID 64
#define C1 256   // 4 heads * 64
#define C2 128   // 2 heads * 64

typedef unsigned int uint32;
typedef __bf16 bf16x8 __attribute__((ext_vector_type(8)));
typedef float f32x4 __attribute__((ext_vector_type(4)));

static __device__ __forceinline__ float bf2f(unsigned short u){
    return __uint_as_float(((uint32)u) << 16);
}
static __device__ __forceinline__ unsigned short f2bf(float x){
    uint32 u = __float_as_uint(x);
    return (unsigned short)((u + 0x7FFFu + ((u >> 16) & 1u)) >> 16);
}
static __device__ __forceinline__ uint32 pack2(float a, float b){
    return (uint32)f2bf(a) | ((uint32)f2bf(b) << 16);
}

// ---------------- CSR build ----------------
__global__ void k_zero(int* deg, int* cur, int N){
    int i = blockIdx.x*256 + threadIdx.x;
    if (i < N){ deg[i] = 0; cur[i] = 0; }
}
__global__ void k_hist(const int* __restrict__ ei, int* deg, int E){
    int i = blockIdx.x*256 + threadIdx.x;
    if (i < E) atomicAdd(&deg[ei[E + i]], 1);
}
__global__ void k_scan1(const int* __restrict__ deg, int* rowptr, int* part, int N){
    __shared__ int s[256];
    int tid = threadIdx.x;
    int i = blockIdx.x*256 + tid;
    int v = (i < N) ? deg[i] : 0;
    s[tid] = v; __syncthreads();
    for (int off = 1; off < 256; off <<= 1){
        int t = (tid >= off) ? s[tid - off] : 0;
        __syncthreads();
        s[tid] += t;
        __syncthreads();
    }
    if (i < N) rowptr[i] = s[tid] - v;
    if (tid == 255) part[blockIdx.x] = s[tid];
}
__global__ void k_scan2(int* part, int nb){
    __shared__ int s[512];
    int tid = threadIdx.x;
    int v = (tid < nb) ? part[tid] : 0;
    s[tid] = v; __syncthreads();
    for (int off = 1; off < 512; off <<= 1){
        int t = (tid >= off) ? s[tid - off] : 0;
        __syncthreads();
        s[tid] += t;
        __syncthreads();
    }
    if (tid < nb) part[tid] = s[tid] - v;
}
__global__ void k_scan3(int* rowptr, const int* __restrict__ part, int N, int E){
    int i = blockIdx.x*256 + threadIdx.x;
    if (i < N) rowptr[i] += part[blockIdx.x];
    if (i == 0) rowptr[N] = E;
}
__global__ void k_scatter(const int* __restrict__ ei, const int* __restrict__ rowptr,
                          int* cur, int* colx, int* dstx, int E){
    int i = blockIdx.x*256 + threadIdx.x;
    if (i < E){
        int d = ei[E + i];
        int pos = atomicAdd(&cur[d], 1);
        int p = rowptr[d] + pos;
        colx[p] = ei[i];
        dstx[p] = d;
    }
}

// ---------------- weight pre-swizzle: contiguous-k fragment order ----------------
__global__ __launch_bounds__(256) void k_cvtW(const float* __restrict__ W,
        unsigned short* __restrict__ Wf, int ncol, int ntiles, int nunits){
    int unit = blockIdx.x*4 + (threadIdx.x >> 6);
    if (unit >= nunits) return;
    int l = threadIdx.x & 63;
    int s = unit / ntiles, ct = unit % ntiles;
    int col = ct*16 + (l & 15);
    int g = l >> 4;
    unsigned short o[8];
    #pragma unroll
    for (int j = 0; j < 8; j++){
        int k = s*32 + g*8 + j;
        o[j] = f2bf(W[(size_t)k*ncol + col]);
    }
    ushort4* dst = (ushort4*)&Wf[((size_t)unit*64 + l)*8];
    dst[0] = make_ushort4(o[0], o[1], o[2], o[3]);
    dst[1] = make_ushort4(o[4], o[5], o[6], o[7]);
}

// ---------------- constant precompute: pad bias, emotion gate ----------
__global__ __launch_bounds__(256) void k_prep(const float* __restrict__ W1,
        const float* __restrict__ pad, const float* __restrict__ gw, const float* __restrict__ gb,
        float* __restrict__ c1v, float* __restrict__ gate){
    int tid = threadIdx.x;
    c1v[tid] = pad[0]*W1[(size_t)(IN_DIM+0)*C1 + tid]
             + pad[1]*W1[(size_t)(IN_DIM+1)*C1 + tid]
             + pad[2]*W1[(size_t)(IN_DIM+2)*C1 + tid];
    if (tid < HID){
        float g = pad[0]*gw[0*HID + tid] + pad[1]*gw[1*HID + tid] + pad[2]*gw[2*HID + tid] + gb[tid];
        gate[tid] = 1.f/(1.f + __expf(-g));
    }
}

// ---------------- GEMM1 (MFMA): h1 = [x|pad]@W1 + fused al1 epilogue ----------------
__global__ __launch_bounds__(256) void k_gemm1_mfma(const float* __restrict__ x,
        const unsigned short* __restrict__ Wf, const float* __restrict__ c1v,
        const float* __restrict__ as1, const float* __restrict__ ad1,
        unsigned short* __restrict__ h1, float* __restrict__ als, float* __restrict__ ald, int N)
{
    __shared__ unsigned short Af[2][8*64*8];   // 2 x 8KB
    const int tid = threadIdx.x;
    const int l   = tid & 63;
    const int w   = tid >> 6;
    const int n0  = blockIdx.x * 128;

    const int srow = tid & 127;
    const int jh   = tid >> 7;
    const int srt  = srow >> 4, srr = srow & 15;
    const int d0   = (srt*64 + (jh*2+0)*16 + srr)*8;
    const int d1   = (srt*64 + (jh*2+1)*16 + srr)*8;
    int crow = n0 + srow; if (crow > N-1) crow = N-1;
    const float* xrow = x + (size_t)crow*IN_DIM + jh*16;

    f32x4 acc[4][8];
    #pragma unroll
    for (int i = 0; i < 4; i++)
        #pragma unroll
        for (int rt = 0; rt < 8; rt++)
            acc[i][rt] = (f32x4){0.f, 0.f, 0.f, 0.f};

    float4 ra, rb, rc, rd;
    uint4 wcur[4], wnxt[4];

    ra = *(const float4*)(xrow + 0); rb = *(const float4*)(xrow + 4);
    rc = *(const float4*)(xrow + 8); rd = *(const float4*)(xrow + 12);
    {
        uint4 u0, u1;
        u0.x = pack2(ra.x, ra.y); u0.y = pack2(ra.z, ra.w);
        u0.z = pack2(rb.x, rb.y); u0.w = pack2(rb.z, rb.w);
        u1.x = pack2(rc.x, rc.y); u1.y = pack2(rc.z, rc.w);
        u1.z = pack2(rd.x, rd.y); u1.w = pack2(rd.z, rd.w);
        *(uint4*)&Af[0][d0] = u0;
        *(uint4*)&Af[0][d1] = u1;
    }
    {
        const unsigned short* p = Wf + ((size_t)(w*4)*64 + l)*8;
        #pragma unroll
        for (int i = 0; i < 4; i++) wcur[i] = *(const uint4*)(p + (size_t)i*512);
    }
    __syncthreads();

    for (int s = 0; s < 12; ++s){
        if (s < 11){
            const float* src = xrow + (s+1)*32;
            ra = *(const float4*)(src + 0); rb = *(const float4*)(src + 4);
            rc = *(const float4*)(src + 8); rd = *(const float4*)(src + 12);
            const unsigned short* p = Wf + ((size_t)((s+1)*16 + w*4)*64 + l)*8;
            #pragma unroll
            for (int i = 0; i < 4; i++) wnxt[i] = *(const uint4*)(p + (size_t)i*512);
        }
        bf16x8 af[8];
        #pragma unroll
        for (int rt = 0; rt < 8; rt++)
            af[rt] = __builtin_bit_cast(bf16x8, *(const uint4*)&Af[s&1][(rt*64 + l)*8]);
        #pragma unroll
        for (int i = 0; i < 4; i++){
            bf16x8 bw = __builtin_bit_cast(bf16x8, wcur[i]);
            #pragma unroll
            for (int rt = 0; rt < 8; rt++)
                acc[i][rt] = __builtin_amdgcn_mfma_f32_16x16x32_bf16(bw, af[rt], acc[i][rt], 0, 0, 0);
        }
        if (s < 11){
            uint4 u0, u1;
            u0.x = pack2(ra.x, ra.y); u0.y = pack2(ra.z, ra.w);
            u0.z = pack2(rb.x, rb.y); u0.w = pack2(rb.z, rb.w);
            u1.x = pack2(rc.x, rc.y); u1.y = pack2(rc.z, rc.w);
            u1.z = pack2(rd.x, rd.y); u1.w = pack2(rd.z, rd.w);
            *(uint4*)&Af[(s+1)&1][d0] = u0;
            *(uint4*)&Af[(s+1)&1][d1] = u1;
            __syncthreads();
            #pragma unroll
            for (int i = 0; i < 4; i++) wcur[i] = wnxt[i];
        }
    }

    const int g = l >> 4;
    float4 cvv[4], av[4], dv[4];
    #pragma unroll
    for (int i = 0; i < 4; i++){
        int cl = i*16 + g*4;
        cvv[i] = *(const float4*)&c1v[w*64 + cl];
        av[i]  = *(const float4*)&as1[w*64 + cl];
        dv[i]  = *(const float4*)&ad1[w*64 + cl];
    }
    #pragma unroll
    for (int rt = 0; rt < 8; rt++){
        int node = n0 + rt*16 + (l & 15);
        bool ok = node < N;
        float ps = 0.f, pd = 0.f;
        #pragma unroll
        for (int i = 0; i < 4; i++){
            float h0 = acc[i][rt][0] + cvv[i].x;
            float h1v = acc[i][rt][1] + cvv[i].y;
            float h2v = acc[i][rt][2] + cvv[i].z;
            float h3v = acc[i][rt][3] + cvv[i].w;
            ps += h0*av[i].x + h1v*av[i].y + h2v*av[i].z + h3v*av[i].w;
            pd += h0*dv[i].x + h1v*dv[i].y + h2v*dv[i].z + h3v*dv[i].w;
            if (ok){
                ushort4 o = make_ushort4(f2bf(h0), f2bf(h1v), f2bf(h2v), f2bf(h3v));
                *(ushort4*)&h1[(size_t)node*C1 + w*64 + i*16 + g*4] = o;
            }
        }
        ps += __shfl_xor(ps, 16, 64); ps += __shfl_xor(ps, 32, 64);
        pd += __shfl_xor(pd, 16, 64); pd += __shfl_xor(pd, 32, 64);
        if (ok && g == 0){
            als[(size_t)node*4 + w] = ps;
            ald[(size_t)node*4 + w] = pd;
        }
    }
}

// ---------------- GEMM2 (MFMA): h2 = x2 @ W2 + fused al2 epilogue ----------------
__global__ __launch_bounds__(256) void k_gemm2_mfma(const unsigned short* __restrict__ x2,
        const unsigned short* __restrict__ Wf,
        const float* __restrict__ as2, const float* __restrict__ ad2,
        unsigned short* __restrict__ h2, float* __restrict__ als, float* __restrict__ ald, int N)
{
    __shared__ unsigned short Af[2][8*64*8];
    const int tid = threadIdx.x;
    const int l   = tid & 63;
    const int w   = tid >> 6;
    const int wr  = w >> 1, wc = w & 1;
    const int n0  = blockIdx.x * 128;

    const int srow = tid >> 1;
    const int half = tid & 1;
    const int srt  = srow >> 4, srr = srow & 15;
    const int d0   = (srt*64 + (half*2+0)*16 + srr)*8;
    const int d1   = d0 + 128;
    int crow = n0 + srow; if (crow > N-1) crow = N-1;
    const unsigned short* xrow = x2 + (size_t)crow*C1 + half*16;

    f32x4 acc[4][4];
    #pragma unroll
    for (int i = 0; i < 4; i++)
        #pragma unroll
        for (int rt = 0; rt < 4; rt++)
            acc[i][rt] = (f32x4){0.f, 0.f, 0.f, 0.f};

    uint4 p0, p1, wcur[4], wnxt[4];
    p0 = *(const uint4*)(xrow + 0);
    p1 = *(const uint4*)(xrow + 8);
    *(uint4*)&Af[0][d0] = p0;
    *(uint4*)&Af[0][d1] = p1;
    {
        const unsigned short* p = Wf + ((size_t)(wc*4)*64 + l)*8;
        #pragma unroll
        for (int i = 0; i < 4; i++) wcur[i] = *(const uint4*)(p + (size_t)i*512);
    }
    __syncthreads();

    for (int s = 0; s < 8; ++s){
        if (s < 7){
            p0 = *(const uint4*)(xrow + (s+1)*32);
            p1 = *(const uint4*)(xrow + (s+1)*32 + 8);
            const unsigned short* p = Wf + ((size_t)((s+1)*8 + wc*4)*64 + l)*8;
            #pragma unroll
            for (int i = 0; i < 4; i++) wnxt[i] = *(const uint4*)(p + (size_t)i*512);
        }
        bf16x8 af[4];
        #pragma unroll
        for (int rt = 0; rt < 4; rt++)
            af[rt] = __builtin_bit_cast(bf16x8, *(const uint4*)&Af[s&1][((wr*4 + rt)*64 + l)*8]);
        #pragma unroll
        for (int i = 0; i < 4; i++){
            bf16x8 bw = __builtin_bit_cast(bf16x8, wcur[i]);
            #pragma unroll
            for (int rt = 0; rt < 4; rt++)
                acc[i][rt] = __builtin_amdgcn_mfma_f32_16x16x32_bf16(bw, af[rt], acc[i][rt], 0, 0, 0);
        }
        if (s < 7){
            *(uint4*)&Af[(s+1)&1][d0] = p0;
            *(uint4*)&Af[(s+1)&1][d1] = p1;
            __syncthreads();
            #pragma unroll
            for (int i = 0; i < 4; i++) wcur[i] = wnxt[i];
        }
    }

    const int g = l >> 4;
    float4 av[4], dv[4];
    #pragma unroll
    for (int i = 0; i < 4; i++){
        int cl = i*16 + g*4;
        av[i] = *(const float4*)&as2[wc*64 + cl];
        dv[i] = *(const float4*)&ad2[wc*64 + cl];
    }
    #pragma unroll
    for (int rt = 0; rt < 4; rt++){
        int node = n0 + wr*64 + rt*16 + (l & 15);
        bool ok = node < N;
        float ps = 0.f, pd = 0.f;
        #pragma unroll
        for (int i = 0; i < 4; i++){
            float h0 = acc[i][rt][0], h1v = acc[i][rt][1];
            float h2v = acc[i][rt][2], h3v = acc[i][rt][3];
            ps += h0*av[i].x + h1v*av[i].y + h2v*av[i].z + h3v*av[i].w;
            pd += h0*dv[i].x + h1v*dv[i].y + h2v*dv[i].z + h3v*dv[i].w;
            if (ok){
                ushort4 o = make_ushort4(f2bf(h0), f2bf(h1v), f2bf(h2v), f2bf(h3v));
                *(ushort4*)&h2[(size_t)node*C2 + wc*64 + i*16 + g*4] = o;
            }
        }
        ps += __shfl_xor(ps, 16, 64); ps += __shfl_xor(ps, 32, 64);
        pd += __shfl_xor(pd, 16, 64); pd += __shfl_xor(pd, 32, 64);
        if (ok && g == 0){
            als[(size_t)node*2 + wc] = ps;
            ald[(size_t)node*2 + wc] = pd;
        }
    }
}

// ---------------- A: edge-parallel logits e = leaky(als[src]+ald[dst]) ----------------
template<int H>
__global__ __launch_bounds__(256) void k_elogit(const int* __restrict__ colx,
        const int* __restrict__ dstx, const float* __restrict__ als,
        const float* __restrict__ ald, float* __restrict__ ep, int E)
{
    int i = blockIdx.x*256 + threadIdx.x;
    if (i >= E) return;
    int s = colx[i], d = dstx[i];
    if constexpr (H == 4){
        float4 a = *(const float4*)&als[(size_t)s*4];
        float4 b = *(const float4*)&ald[(size_t)d*4];
        float4 e;
        e.x = a.x + b.x; e.x = fmaxf(e.x, 0.2f*e.x);
        e.y = a.y + b.y; e.y = fmaxf(e.y, 0.2f*e.y);
        e.z = a.z + b.z; e.z = fmaxf(e.z, 0.2f*e.z);
        e.w = a.w + b.w; e.w = fmaxf(e.w, 0.2f*e.w);
        *(float4*)&ep[(size_t)i*4] = e;
    } else {
        float2 a = *(const float2*)&als[(size_t)s*2];
        float2 b = *(const float2*)&ald[(size_t)d*2];
        float2 e;
        e.x = a.x + b.x; e.x = fmaxf(e.x, 0.2f*e.x);
        e.y = a.y + b.y; e.y = fmaxf(e.y, 0.2f*e.y);
        *(float2*)&ep[(size_t)i*2] = e;
    }
}

// ---------------- B: thread per (node,head) segment softmax; ep <- p (in place) -------
template<int H>
__global__ __launch_bounds__(256) void k_segsm(const int* __restrict__ rowptr,
        const float* __restrict__ als, const float* __restrict__ ald,
        float* __restrict__ ep, float* __restrict__ den, float* __restrict__ pSelf, int NH)
{
    int t = blockIdx.x*256 + threadIdx.x;
    if (t >= NH) return;
    int node = t / H;
    int head = t - node*H;
    int base = rowptr[node];
    int cnt  = rowptr[node+1] - base;
    float es = als[t] + ald[t];
    es = fmaxf(es, 0.2f*es);
    float m = es;
    for (int j = 0; j < cnt; j++)
        m = fmaxf(m, ep[(size_t)(base + j)*H + head]);
    float ps = __expf(es - m);
    float dn = ps;
    for (int j = 0; j < cnt; j++){
        size_t idx = (size_t)(base + j)*H + head;
        float p = __expf(ep[idx] - m);
        ep[idx] = p;
        dn += p;
    }
    den[t]   = dn;
    pSelf[t] = ps;
}

// ---------------- C: wave-per-node weighted gather-sum (no softmax in loop) ----------
template<int H, int CPL, int LAYER>
__global__ __launch_bounds__(256) void k_gat(const unsigned short* __restrict__ hlin,
        const float* __restrict__ ep, const float* __restrict__ den, const float* __restrict__ pSelf,
        const int* __restrict__ rowptr, const int* __restrict__ colx,
        const float* __restrict__ bias,
        const float* __restrict__ gate, const float* __restrict__ aw1,
        const float* __restrict__ ab1, const float* __restrict__ aw2, const float* __restrict__ ab2,
        unsigned short* __restrict__ out_bf, float* __restrict__ out_f,
        float* __restrict__ attn, int N)
{
    constexpr int C = H*64;
    constexpr uint32 RB = C*2;               // bf16 row bytes
    __shared__ float hs[4][C2];
    int lane = threadIdx.x & 63, wid = threadIdx.x >> 6;
    int n = blockIdx.x*4 + wid;
    if (n >= N) return;
    const int c0 = lane*CPL;
    const int head = c0 >> 6;
    const int base = rowptr[n];
    const int cnt  = rowptr[n+1] - base;
    const char* hbase = (const char*)hlin + (uint32)c0*2;

    float acc[CPL];
    {
        float psf = pSelf[(uint32)n*H + head];
        if constexpr (CPL == 4){
            ushort4 v = *(const ushort4*)(hbase + (size_t)(uint32)n*RB);
            acc[0] = psf*bf2f(v.x); acc[1] = psf*bf2f(v.y);
            acc[2] = psf*bf2f(v.z); acc[3] = psf*bf2f(v.w);
        } else {
            uint32 v = *(const uint32*)(hbase + (size_t)(uint32)n*RB);
            acc[0] = psf*bf2f((unsigned short)(v & 0xffff));
            acc[1] = psf*bf2f((unsigned short)(v >> 16));
        }
    }
    for (int i = 0; i < cnt; i += 4){
        int idx[4], sk[4];
        #pragma unroll
        for (int k = 0; k < 4; k++){
            int ii = i + k; if (ii > cnt-1) ii = cnt-1;
            idx[k] = base + ii;
        }
        #pragma unroll
        for (int k = 0; k < 4; k++) sk[k] = colx[idx[k]];
        float pk[4];
        #pragma unroll
        for (int k = 0; k < 4; k++){
            float pv = ep[(size_t)(uint32)idx[k]*H + head];   // position-indexed: no colx dep
            pk[k] = (i + k < cnt) ? pv : 0.f;
        }
        if constexpr (CPL == 4){
            ushort4 h4[4];
            #pragma unroll
            for (int k = 0; k < 4; k++) h4[k] = *(const ushort4*)(hbase + (size_t)(uint32)sk[k]*RB);
            #pragma unroll
            for (int k = 0; k < 4; k++){
                acc[0] += pk[k]*bf2f(h4[k].x);
                acc[1] += pk[k]*bf2f(h4[k].y);
                acc[2] += pk[k]*bf2f(h4[k].z);
                acc[3] += pk[k]*bf2f(h4[k].w);
            }
        } else {
            uint32 h2v[4];
            #pragma unroll
            for (int k = 0; k < 4; k++) h2v[k] = *(const uint32*)(hbase + (size_t)(uint32)sk[k]*RB);
            #pragma unroll
            for (int k = 0; k < 4; k++){
                acc[0] += pk[k]*bf2f((unsigned short)(h2v[k] & 0xffff));
                acc[1] += pk[k]*bf2f((unsigned short)(h2v[k] >> 16));
            }
        }
    }

    float inv = 1.f/(den[(uint32)n*H + head] + 1e-16f);
    if constexpr (LAYER == 1){
        unsigned short o[CPL];
        #pragma unroll
        for (int j = 0; j < CPL; j++){
            float r = acc[j]*inv + bias[c0 + j];
            r = (r > 0.f) ? r : (__expf(r) - 1.f);   // elu
            o[j] = f2bf(r);
        }
        if constexpr (CPL == 4){
            ushort4 ov; ov.x = o[0]; ov.y = o[1]; ov.z = o[2]; ov.w = o[3];
            *(ushort4*)&out_bf[(size_t)n*C + c0] = ov;
        }
    } else {
        #pragma unroll
        for (int j = 0; j < CPL; j++){
            float r = acc[j]*inv + bias[c0 + j];
            r = (r > 0.f) ? r : (__expf(r) - 1.f);   // elu
            float o = r*gate[(c0 + j) & 63];
            out_f[(size_t)n*C + c0 + j] = o;
            hs[wid][c0 + j] = o;
        }
        // fused attention-score MLP: native aw1 layout [C2][HID] -> coalesced loads
        // (lane l owns hidden unit l; aw1[c*HID+l] is 1 cache line per instr across the wave)
        float a = ab1[lane];
        #pragma unroll 4
        for (int c = 0; c < C2; c++) a += hs[wid][c]*aw1[(size_t)c*HID + lane];
        a = fmaxf(a, 0.f);
        float part = a*aw2[lane];
        #pragma unroll
        for (int mm = 32; mm >= 1; mm >>= 1) part += __shfl_xor(part, mm, 64);
        if (lane == 0) attn[n] = 1.f/(1.f + __expf(-(part + ab2[0])));
    }
}

extern "C" void kernel_launch(void* const* d_in, const int* in_sizes, int n_in,
                              void* d_out, int out_size, void* d_ws, size_t ws_size,
                              hipStream_t stream)
{
    const float* x    = (const float*)d_in[0];
    const int*   ei   = (const int*)  d_in[1];
    const float* pad  = (const float*)d_in[2];
    const float* W1   = (const float*)d_in[3];
    const float* as1  = (const float*)d_in[4];
    const float* ad1  = (const float*)d_in[5];
    const float* b1   = (const float*)d_in[6];
    const float* W2   = (const float*)d_in[7];
    const float* as2  = (const float*)d_in[8];
    const float* ad2  = (const float*)d_in[9];
    const float* b2   = (const float*)d_in[10];
    const float* aw1  = (const float*)d_in[11];
    const float* ab1  = (const float*)d_in[12];
    const float* aw2  = (const float*)d_in[13];
    const float* ab2  = (const float*)d_in[14];
    const float* gw   = (const float*)d_in[15];
    const float* gb   = (const float*)d_in[16];

    const int N = in_sizes[0] / IN_DIM;
    const int E = in_sizes[1] / 2;

    float* outh    = (float*)d_out;
    float* outattn = outh + (size_t)N*C2;

    char* w = (char*)d_ws;
    auto alloc = [&](size_t bytes)->char*{
        char* p = w;
        w += (bytes + 255) & ~(size_t)255;
        return p;
    };
    unsigned short* h1  = (unsigned short*)alloc((size_t)N*C1*2);
    unsigned short* x2  = (unsigned short*)alloc((size_t)N*C1*2);
    unsigned short* h2  = (unsigned short*)alloc((size_t)N*C2*2);
    float* als1 = (float*)alloc((size_t)N*4*4);
    float* ald1 = (float*)alloc((size_t)N*4*4);
    float* als2 = (float*)alloc((size_t)N*2*4);
    float* ald2 = (float*)alloc((size_t)N*2*4);
    int* deg    = (int*)alloc((size_t)N*4);
    int* cur    = (int*)alloc((size_t)N*4);
    int* rowptr = (int*)alloc((size_t)(N+1)*4);
    int* colx   = (int*)alloc((size_t)E*4);
    int* dstx   = (int*)alloc((size_t)E*4);
    int* part   = (int*)alloc(512*4);
    unsigned short* Wf1 = (unsigned short*)alloc((size_t)12*16*64*8*2);
    unsigned short* Wf2 = (unsigned short*)alloc((size_t)8*8*64*8*2);
    float* c1v  = (float*)alloc(C1*4);
    float* gate = (float*)alloc(HID*4);

    // Lifetime-based aliases (no new footprint):
    // layer-1 softmax scratch lives in the (not yet written) h2 buffer.
    float* ep1    = (float*)h2;                                   // E*4 floats
    float* den1   = (float*)((char*)h2 + (size_t)E*16);           // N*4 floats
    float* pSelf1 = (float*)((char*)h2 + (size_t)E*16 + (size_t)N*16);
    // layer-2 softmax scratch lives in x2 (dead after gemm2 reads it).
    float* ep2    = (float*)x2;                                   // E*2 floats
    float* den2   = (float*)((char*)x2 + (size_t)E*8);            // N*2 floats
    float* pSelf2 = (float*)((char*)x2 + (size_t)E*8 + (size_t)N*8);

    const int nbN = (N + 255)/256;
    const int nbE = (E + 255)/256;
    const int nbW = (N + 3)/4;        // wave-per-node kernels
    const int nbG = (N + 127)/128;    // gemm row blocks

    // weight swizzles + constants (independent of CSR)
    k_cvtW <<<(192+3)/4, 256, 0, stream>>>(W1, Wf1, C1, 16, 192);
    k_cvtW <<<(64+3)/4,  256, 0, stream>>>(W2, Wf2, C2, 8, 64);
    k_prep <<<1, 256, 0, stream>>>(W1, pad, gw, gb, c1v, gate);

    // CSR by destination
    k_zero   <<<nbN, 256, 0, stream>>>(deg, cur, N);
    k_hist   <<<nbE, 256, 0, stream>>>(ei, deg, E);
    k_scan1  <<<nbN, 256, 0, stream>>>(deg, rowptr, part, N);
    k_scan2  <<<1, 512, 0, stream>>>(part, nbN);
    k_scan3  <<<nbN, 256, 0, stream>>>(rowptr, part, N, E);
    k_scatter<<<nbE, 256, 0, stream>>>(ei, rowptr, cur, colx, dstx, E);

    // ---- layer 1 ----
    k_gemm1_mfma<<<nbG, 256, 0, stream>>>(x, Wf1, c1v, as1, ad1, h1, als1, ald1, N);
    k_elogit<4><<<nbE, 256, 0, stream>>>(colx, dstx, als1, ald1, ep1, E);
    k_segsm<4> <<<(N*4 + 255)/256, 256, 0, stream>>>(rowptr, als1, ald1, ep1, den1, pSelf1, N*4);
    k_gat<4,4,1><<<nbW, 256, 0, stream>>>(h1, ep1, den1, pSelf1, rowptr, colx, b1,
                                          nullptr, nullptr, nullptr, nullptr, nullptr,
                                          x2, nullptr, nullptr, N);

    // ---- layer 2 ----
    k_gemm2_mfma<<<nbG, 256, 0, stream>>>(x2, Wf2, as2, ad2, h2, als2, ald2, N);
    k_elogit<2><<<nbE, 256, 0, stream>>>(colx, dstx, als2, ald2, ep2, E);
    k_segsm<2> <<<(N*2 + 255)/256, 256, 0, stream>>>(rowptr, als2, ald2, ep2, den2, pSelf2, N*2);
    k_gat<2,2,2><<<nbW, 256, 0, stream>>>(h2, ep2, den2, pSelf2, rowptr, colx, b2,
                                          gate, aw1, ab1, aw2, ab2,
                                          nullptr, outh, outattn, N);
}

// Round 7
// 309.284 us; speedup vs baseline: 2.0731x; 1.2832x over previous
//
#include <hip/hip_runtime.h>
#include <hip/hip_bf16.h>
#include <stdint.h>

#define IN_DIM 384
#define HID 64
#define C1 256   // 4 heads * 64
#define C2 128   // 2 heads * 64

typedef unsigned int uint32;
typedef __bf16 bf16x8 __attribute__((ext_vector_type(8)));
typedef float f32x4 __attribute__((ext_vector_type(4)));

static __device__ __forceinline__ float bf2f(unsigned short u){
    return __uint_as_float(((uint32)u) << 16);
}
static __device__ __forceinline__ unsigned short f2bf(float x){
    uint32 u = __float_as_uint(x);
    return (unsigned short)((u + 0x7FFFu + ((u >> 16) & 1u)) >> 16);
}
static __device__ __forceinline__ uint32 pack2(float a, float b){
    return (uint32)f2bf(a) | ((uint32)f2bf(b) << 16);
}

// ---------------- CSR build ----------------
__global__ void k_zero(int* deg, int* cur, int N){
    int i = blockIdx.x*256 + threadIdx.x;
    if (i < N){ deg[i] = 0; cur[i] = 0; }
}
__global__ void k_hist(const int* __restrict__ ei, int* deg, int E){
    int i = blockIdx.x*256 + threadIdx.x;
    if (i < E) atomicAdd(&deg[ei[E + i]], 1);
}
__global__ void k_scan1(const int* __restrict__ deg, int* rowptr, int* part, int N){
    __shared__ int s[256];
    int tid = threadIdx.x;
    int i = blockIdx.x*256 + tid;
    int v = (i < N) ? deg[i] : 0;
    s[tid] = v; __syncthreads();
    for (int off = 1; off < 256; off <<= 1){
        int t = (tid >= off) ? s[tid - off] : 0;
        __syncthreads();
        s[tid] += t;
        __syncthreads();
    }
    if (i < N) rowptr[i] = s[tid] - v;
    if (tid == 255) part[blockIdx.x] = s[tid];
}
__global__ void k_scan2(int* part, int nb){
    __shared__ int s[512];
    int tid = threadIdx.x;
    int v = (tid < nb) ? part[tid] : 0;
    s[tid] = v; __syncthreads();
    for (int off = 1; off < 512; off <<= 1){
        int t = (tid >= off) ? s[tid - off] : 0;
        __syncthreads();
        s[tid] += t;
        __syncthreads();
    }
    if (tid < nb) part[tid] = s[tid] - v;
}
__global__ void k_scan3(int* rowptr, const int* __restrict__ part, int N, int E){
    int i = blockIdx.x*256 + threadIdx.x;
    if (i < N) rowptr[i] += part[blockIdx.x];
    if (i == 0) rowptr[N] = E;
}
__global__ void k_scatter(const int* __restrict__ ei, const int* __restrict__ rowptr,
                          int* cur, int* colx, int* dstx, int E){
    int i = blockIdx.x*256 + threadIdx.x;
    if (i < E){
        int d = ei[E + i];
        int pos = atomicAdd(&cur[d], 1);
        int p = rowptr[d] + pos;
        colx[p] = ei[i];
        dstx[p] = d;
    }
}

// ---------------- weight pre-swizzle: contiguous-k fragment order ----------------
// Wf[unit = s*ntiles+ct][lane l][j] = W[k = s*32 + 8*(l>>4) + j][ct*16 + (l&15)]
__global__ __launch_bounds__(256) void k_cvtW(const float* __restrict__ W,
        unsigned short* __restrict__ Wf, int ncol, int ntiles, int nunits){
    int unit = blockIdx.x*4 + (threadIdx.x >> 6);
    if (unit >= nunits) return;
    int l = threadIdx.x & 63;
    int s = unit / ntiles, ct = unit % ntiles;
    int col = ct*16 + (l & 15);
    int g = l >> 4;
    unsigned short o[8];
    #pragma unroll
    for (int j = 0; j < 8; j++){
        int k = s*32 + g*8 + j;
        o[j] = f2bf(W[(size_t)k*ncol + col]);
    }
    ushort4* dst = (ushort4*)&Wf[((size_t)unit*64 + l)*8];
    dst[0] = make_ushort4(o[0], o[1], o[2], o[3]);
    dst[1] = make_ushort4(o[4], o[5], o[6], o[7]);
}

// ---------------- constant precompute: pad bias, emotion gate ----------
__global__ __launch_bounds__(256) void k_prep(const float* __restrict__ W1,
        const float* __restrict__ pad, const float* __restrict__ gw, const float* __restrict__ gb,
        float* __restrict__ c1v, float* __restrict__ gate){
    int tid = threadIdx.x;
    c1v[tid] = pad[0]*W1[(size_t)(IN_DIM+0)*C1 + tid]
             + pad[1]*W1[(size_t)(IN_DIM+1)*C1 + tid]
             + pad[2]*W1[(size_t)(IN_DIM+2)*C1 + tid];
    if (tid < HID){
        float g = pad[0]*gw[0*HID + tid] + pad[1]*gw[1*HID + tid] + pad[2]*gw[2*HID + tid] + gb[tid];
        gate[tid] = 1.f/(1.f + __expf(-g));
    }
}

// ---------------- GEMM1 (MFMA): h1 = [x|pad]@W1 + fused al1 epilogue ----------------
__global__ __launch_bounds__(256) void k_gemm1_mfma(const float* __restrict__ x,
        const unsigned short* __restrict__ Wf, const float* __restrict__ c1v,
        const float* __restrict__ as1, const float* __restrict__ ad1,
        unsigned short* __restrict__ h1, float* __restrict__ als, float* __restrict__ ald, int N)
{
    __shared__ unsigned short Af[2][8*64*8];   // 2 x 8KB
    const int tid = threadIdx.x;
    const int l   = tid & 63;
    const int w   = tid >> 6;
    const int n0  = blockIdx.x * 128;

    const int srow = tid & 127;
    const int jh   = tid >> 7;
    const int srt  = srow >> 4, srr = srow & 15;
    const int d0   = (srt*64 + (jh*2+0)*16 + srr)*8;
    const int d1   = (srt*64 + (jh*2+1)*16 + srr)*8;
    int crow = n0 + srow; if (crow > N-1) crow = N-1;
    const float* xrow = x + (size_t)crow*IN_DIM + jh*16;

    f32x4 acc[4][8];
    #pragma unroll
    for (int i = 0; i < 4; i++)
        #pragma unroll
        for (int rt = 0; rt < 8; rt++)
            acc[i][rt] = (f32x4){0.f, 0.f, 0.f, 0.f};

    float4 ra, rb, rc, rd;
    uint4 wcur[4], wnxt[4];

    ra = *(const float4*)(xrow + 0); rb = *(const float4*)(xrow + 4);
    rc = *(const float4*)(xrow + 8); rd = *(const float4*)(xrow + 12);
    {
        uint4 u0, u1;
        u0.x = pack2(ra.x, ra.y); u0.y = pack2(ra.z, ra.w);
        u0.z = pack2(rb.x, rb.y); u0.w = pack2(rb.z, rb.w);
        u1.x = pack2(rc.x, rc.y); u1.y = pack2(rc.z, rc.w);
        u1.z = pack2(rd.x, rd.y); u1.w = pack2(rd.z, rd.w);
        *(uint4*)&Af[0][d0] = u0;
        *(uint4*)&Af[0][d1] = u1;
    }
    {
        const unsigned short* p = Wf + ((size_t)(w*4)*64 + l)*8;
        #pragma unroll
        for (int i = 0; i < 4; i++) wcur[i] = *(const uint4*)(p + (size_t)i*512);
    }
    __syncthreads();

    for (int s = 0; s < 12; ++s){
        if (s < 11){
            const float* src = xrow + (s+1)*32;
            ra = *(const float4*)(src + 0); rb = *(const float4*)(src + 4);
            rc = *(const float4*)(src + 8); rd = *(const float4*)(src + 12);
            const unsigned short* p = Wf + ((size_t)((s+1)*16 + w*4)*64 + l)*8;
            #pragma unroll
            for (int i = 0; i < 4; i++) wnxt[i] = *(const uint4*)(p + (size_t)i*512);
        }
        bf16x8 af[8];
        #pragma unroll
        for (int rt = 0; rt < 8; rt++)
            af[rt] = __builtin_bit_cast(bf16x8, *(const uint4*)&Af[s&1][(rt*64 + l)*8]);
        #pragma unroll
        for (int i = 0; i < 4; i++){
            bf16x8 bw = __builtin_bit_cast(bf16x8, wcur[i]);
            #pragma unroll
            for (int rt = 0; rt < 8; rt++)
                acc[i][rt] = __builtin_amdgcn_mfma_f32_16x16x32_bf16(bw, af[rt], acc[i][rt], 0, 0, 0);
        }
        if (s < 11){
            uint4 u0, u1;
            u0.x = pack2(ra.x, ra.y); u0.y = pack2(ra.z, ra.w);
            u0.z = pack2(rb.x, rb.y); u0.w = pack2(rb.z, rb.w);
            u1.x = pack2(rc.x, rc.y); u1.y = pack2(rc.z, rc.w);
            u1.z = pack2(rd.x, rd.y); u1.w = pack2(rd.z, rd.w);
            *(uint4*)&Af[(s+1)&1][d0] = u0;
            *(uint4*)&Af[(s+1)&1][d1] = u1;
            __syncthreads();
            #pragma unroll
            for (int i = 0; i < 4; i++) wcur[i] = wnxt[i];
        }
    }

    const int g = l >> 4;
    float4 cvv[4], av[4], dv[4];
    #pragma unroll
    for (int i = 0; i < 4; i++){
        int cl = i*16 + g*4;
        cvv[i] = *(const float4*)&c1v[w*64 + cl];
        av[i]  = *(const float4*)&as1[w*64 + cl];
        dv[i]  = *(const float4*)&ad1[w*64 + cl];
    }
    #pragma unroll
    for (int rt = 0; rt < 8; rt++){
        int node = n0 + rt*16 + (l & 15);
        bool ok = node < N;
        float ps = 0.f, pd = 0.f;
        #pragma unroll
        for (int i = 0; i < 4; i++){
            float h0 = acc[i][rt][0] + cvv[i].x;
            float h1v = acc[i][rt][1] + cvv[i].y;
            float h2v = acc[i][rt][2] + cvv[i].z;
            float h3v = acc[i][rt][3] + cvv[i].w;
            ps += h0*av[i].x + h1v*av[i].y + h2v*av[i].z + h3v*av[i].w;
            pd += h0*dv[i].x + h1v*dv[i].y + h2v*dv[i].z + h3v*dv[i].w;
            if (ok){
                ushort4 o = make_ushort4(f2bf(h0), f2bf(h1v), f2bf(h2v), f2bf(h3v));
                *(ushort4*)&h1[(size_t)node*C1 + w*64 + i*16 + g*4] = o;
            }
        }
        ps += __shfl_xor(ps, 16, 64); ps += __shfl_xor(ps, 32, 64);
        pd += __shfl_xor(pd, 16, 64); pd += __shfl_xor(pd, 32, 64);
        if (ok && g == 0){
            als[(size_t)node*4 + w] = ps;
            ald[(size_t)node*4 + w] = pd;
        }
    }
}

// ---------------- GEMM2 (MFMA): h2 = x2 @ W2 + fused al2 epilogue ----------------
__global__ __launch_bounds__(256) void k_gemm2_mfma(const unsigned short* __restrict__ x2,
        const unsigned short* __restrict__ Wf,
        const float* __restrict__ as2, const float* __restrict__ ad2,
        unsigned short* __restrict__ h2, float* __restrict__ als, float* __restrict__ ald, int N)
{
    __shared__ unsigned short Af[2][8*64*8];
    const int tid = threadIdx.x;
    const int l   = tid & 63;
    const int w   = tid >> 6;
    const int wr  = w >> 1, wc = w & 1;
    const int n0  = blockIdx.x * 128;

    const int srow = tid >> 1;
    const int half = tid & 1;
    const int srt  = srow >> 4, srr = srow & 15;
    const int d0   = (srt*64 + (half*2+0)*16 + srr)*8;
    const int d1   = d0 + 128;
    int crow = n0 + srow; if (crow > N-1) crow = N-1;
    const unsigned short* xrow = x2 + (size_t)crow*C1 + half*16;

    f32x4 acc[4][4];
    #pragma unroll
    for (int i = 0; i < 4; i++)
        #pragma unroll
        for (int rt = 0; rt < 4; rt++)
            acc[i][rt] = (f32x4){0.f, 0.f, 0.f, 0.f};

    uint4 p0, p1, wcur[4], wnxt[4];
    p0 = *(const uint4*)(xrow + 0);
    p1 = *(const uint4*)(xrow + 8);
    *(uint4*)&Af[0][d0] = p0;
    *(uint4*)&Af[0][d1] = p1;
    {
        const unsigned short* p = Wf + ((size_t)(wc*4)*64 + l)*8;
        #pragma unroll
        for (int i = 0; i < 4; i++) wcur[i] = *(const uint4*)(p + (size_t)i*512);
    }
    __syncthreads();

    for (int s = 0; s < 8; ++s){
        if (s < 7){
            p0 = *(const uint4*)(xrow + (s+1)*32);
            p1 = *(const uint4*)(xrow + (s+1)*32 + 8);
            const unsigned short* p = Wf + ((size_t)((s+1)*8 + wc*4)*64 + l)*8;
            #pragma unroll
            for (int i = 0; i < 4; i++) wnxt[i] = *(const uint4*)(p + (size_t)i*512);
        }
        bf16x8 af[4];
        #pragma unroll
        for (int rt = 0; rt < 4; rt++)
            af[rt] = __builtin_bit_cast(bf16x8, *(const uint4*)&Af[s&1][((wr*4 + rt)*64 + l)*8]);
        #pragma unroll
        for (int i = 0; i < 4; i++){
            bf16x8 bw = __builtin_bit_cast(bf16x8, wcur[i]);
            #pragma unroll
            for (int rt = 0; rt < 4; rt++)
                acc[i][rt] = __builtin_amdgcn_mfma_f32_16x16x32_bf16(bw, af[rt], acc[i][rt], 0, 0, 0);
        }
        if (s < 7){
            *(uint4*)&Af[(s+1)&1][d0] = p0;
            *(uint4*)&Af[(s+1)&1][d1] = p1;
            __syncthreads();
            #pragma unroll
            for (int i = 0; i < 4; i++) wcur[i] = wnxt[i];
        }
    }

    const int g = l >> 4;
    float4 av[4], dv[4];
    #pragma unroll
    for (int i = 0; i < 4; i++){
        int cl = i*16 + g*4;
        av[i] = *(const float4*)&as2[wc*64 + cl];
        dv[i] = *(const float4*)&ad2[wc*64 + cl];
    }
    #pragma unroll
    for (int rt = 0; rt < 4; rt++){
        int node = n0 + wr*64 + rt*16 + (l & 15);
        bool ok = node < N;
        float ps = 0.f, pd = 0.f;
        #pragma unroll
        for (int i = 0; i < 4; i++){
            float h0 = acc[i][rt][0], h1v = acc[i][rt][1];
            float h2v = acc[i][rt][2], h3v = acc[i][rt][3];
            ps += h0*av[i].x + h1v*av[i].y + h2v*av[i].z + h3v*av[i].w;
            pd += h0*dv[i].x + h1v*dv[i].y + h2v*dv[i].z + h3v*dv[i].w;
            if (ok){
                ushort4 o = make_ushort4(f2bf(h0), f2bf(h1v), f2bf(h2v), f2bf(h3v));
                *(ushort4*)&h2[(size_t)node*C2 + wc*64 + i*16 + g*4] = o;
            }
        }
        ps += __shfl_xor(ps, 16, 64); ps += __shfl_xor(ps, 32, 64);
        pd += __shfl_xor(pd, 16, 64); pd += __shfl_xor(pd, 32, 64);
        if (ok && g == 0){
            als[(size_t)node*2 + wc] = ps;
            ald[(size_t)node*2 + wc] = pd;
        }
    }
}

// ---------------- A: edge-parallel logits e = leaky(als[src]+ald[dst]) ----------------
template<int H>
__global__ __launch_bounds__(256) void k_elogit(const int* __restrict__ colx,
        const int* __restrict__ dstx, const float* __restrict__ als,
        const float* __restrict__ ald, float* __restrict__ ep, int E)
{
    int i = blockIdx.x*256 + threadIdx.x;
    if (i >= E) return;
    int s = colx[i], d = dstx[i];
    if constexpr (H == 4){
        float4 a = *(const float4*)&als[(size_t)s*4];
        float4 b = *(const float4*)&ald[(size_t)d*4];
        float4 e;
        e.x = a.x + b.x; e.x = fmaxf(e.x, 0.2f*e.x);
        e.y = a.y + b.y; e.y = fmaxf(e.y, 0.2f*e.y);
        e.z = a.z + b.z; e.z = fmaxf(e.z, 0.2f*e.z);
        e.w = a.w + b.w; e.w = fmaxf(e.w, 0.2f*e.w);
        *(float4*)&ep[(size_t)i*4] = e;
    } else {
        float2 a = *(const float2*)&als[(size_t)s*2];
        float2 b = *(const float2*)&ald[(size_t)d*2];
        float2 e;
        e.x = a.x + b.x; e.x = fmaxf(e.x, 0.2f*e.x);
        e.y = a.y + b.y; e.y = fmaxf(e.y, 0.2f*e.y);
        *(float2*)&ep[(size_t)i*2] = e;
    }
}

// ---------------- B: thread per (node,head) segment softmax; ep <- p (in place) -------
template<int H>
__global__ __launch_bounds__(256) void k_segsm(const int* __restrict__ rowptr,
        const float* __restrict__ als, const float* __restrict__ ald,
        float* __restrict__ ep, float* __restrict__ den, float* __restrict__ pSelf, int NH)
{
    int t = blockIdx.x*256 + threadIdx.x;
    if (t >= NH) return;
    int node = t / H;
    int head = t - node*H;
    int base = rowptr[node];
    int cnt  = rowptr[node+1] - base;
    float es = als[t] + ald[t];
    es = fmaxf(es, 0.2f*es);
    float m = es;
    for (int j = 0; j < cnt; j++)
        m = fmaxf(m, ep[(size_t)(base + j)*H + head]);
    float ps = __expf(es - m);
    float dn = ps;
    for (int j = 0; j < cnt; j++){
        size_t idx = (size_t)(base + j)*H + head;
        float p = __expf(ep[idx] - m);
        ep[idx] = p;
        dn += p;
    }
    den[t]   = dn;
    pSelf[t] = ps;
}

// ---------------- C: wave-per-node weighted gather-sum (no softmax in loop) ----------
template<int H, int CPL, int LAYER>
__global__ __launch_bounds__(256) void k_gat(const unsigned short* __restrict__ hlin,
        const float* __restrict__ ep, const float* __restrict__ den, const float* __restrict__ pSelf,
        const int* __restrict__ rowptr, const int* __restrict__ colx,
        const float* __restrict__ bias, const float* __restrict__ gate,
        unsigned short* __restrict__ out_bf, float* __restrict__ out_f, int N)
{
    constexpr int C = H*64;
    constexpr uint32 RB = C*2;               // bf16 row bytes
    int lane = threadIdx.x & 63, wid = threadIdx.x >> 6;
    int n = blockIdx.x*4 + wid;
    if (n >= N) return;
    const int c0 = lane*CPL;
    const int head = c0 >> 6;
    const int base = rowptr[n];
    const int cnt  = rowptr[n+1] - base;
    const char* hbase = (const char*)hlin + (uint32)c0*2;

    float acc[CPL];
    {
        float psf = pSelf[(uint32)n*H + head];
        if constexpr (CPL == 4){
            ushort4 v = *(const ushort4*)(hbase + (size_t)(uint32)n*RB);
            acc[0] = psf*bf2f(v.x); acc[1] = psf*bf2f(v.y);
            acc[2] = psf*bf2f(v.z); acc[3] = psf*bf2f(v.w);
        } else {
            uint32 v = *(const uint32*)(hbase + (size_t)(uint32)n*RB);
            acc[0] = psf*bf2f((unsigned short)(v & 0xffff));
            acc[1] = psf*bf2f((unsigned short)(v >> 16));
        }
    }
    for (int i = 0; i < cnt; i += 4){
        int idx[4], sk[4];
        #pragma unroll
        for (int k = 0; k < 4; k++){
            int ii = i + k; if (ii > cnt-1) ii = cnt-1;
            idx[k] = base + ii;
        }
        #pragma unroll
        for (int k = 0; k < 4; k++) sk[k] = colx[idx[k]];
        float pk[4];
        #pragma unroll
        for (int k = 0; k < 4; k++){
            float pv = ep[(size_t)(uint32)idx[k]*H + head];   // position-indexed: no colx dep
            pk[k] = (i + k < cnt) ? pv : 0.f;
        }
        if constexpr (CPL == 4){
            ushort4 h4[4];
            #pragma unroll
            for (int k = 0; k < 4; k++) h4[k] = *(const ushort4*)(hbase + (size_t)(uint32)sk[k]*RB);
            #pragma unroll
            for (int k = 0; k < 4; k++){
                acc[0] += pk[k]*bf2f(h4[k].x);
                acc[1] += pk[k]*bf2f(h4[k].y);
                acc[2] += pk[k]*bf2f(h4[k].z);
                acc[3] += pk[k]*bf2f(h4[k].w);
            }
        } else {
            uint32 h2v[4];
            #pragma unroll
            for (int k = 0; k < 4; k++) h2v[k] = *(const uint32*)(hbase + (size_t)(uint32)sk[k]*RB);
            #pragma unroll
            for (int k = 0; k < 4; k++){
                acc[0] += pk[k]*bf2f((unsigned short)(h2v[k] & 0xffff));
                acc[1] += pk[k]*bf2f((unsigned short)(h2v[k] >> 16));
            }
        }
    }

    float inv = 1.f/(den[(uint32)n*H + head] + 1e-16f);
    if constexpr (LAYER == 1){
        unsigned short o[CPL];
        #pragma unroll
        for (int j = 0; j < CPL; j++){
            float r = acc[j]*inv + bias[c0 + j];
            r = (r > 0.f) ? r : (__expf(r) - 1.f);   // elu
            o[j] = f2bf(r);
        }
        if constexpr (CPL == 4){
            ushort4 ov; ov.x = o[0]; ov.y = o[1]; ov.z = o[2]; ov.w = o[3];
            *(ushort4*)&out_bf[(size_t)n*C + c0] = ov;
        }
    } else {
        float o[CPL];
        #pragma unroll
        for (int j = 0; j < CPL; j++){
            float r = acc[j]*inv + bias[c0 + j];
            r = (r > 0.f) ? r : (__expf(r) - 1.f);   // elu
            o[j] = r*gate[(c0 + j) & 63];
        }
        if constexpr (CPL == 2){
            *(float2*)&out_f[(size_t)n*C + c0] = make_float2(o[0], o[1]);
        }
    }
}

// ---------------- attn MLP via MFMA: attn = sigmoid(relu(outh@aw1+ab1)@aw2+ab2) -------
// 128-node tile, 4 waves; wave w -> rowtiles {2w, 2w+1}; K=128 (4 steps), ncol=64 (4 tiles)
__global__ __launch_bounds__(256) void k_attn_mfma(const float* __restrict__ outh,
        const unsigned short* __restrict__ Wfa, const float* __restrict__ ab1,
        const float* __restrict__ aw2, const float* __restrict__ ab2,
        float* __restrict__ attn, int N)
{
    __shared__ unsigned short Af[4*8*64*8];   // 32 KB: [kstep s][rowtile rt][lane][8]
    const int tid = threadIdx.x;
    const int l   = tid & 63;
    const int w   = tid >> 6;
    const int n0  = blockIdx.x * 128;

    // staging: thread covers row tid>>1, k-half (tid&1)*16 of each 32-wide K step
    const int r  = tid >> 1;
    const int kh = tid & 1;
    const int rt8 = r >> 4, rr = r & 15;
    int crow = n0 + r; if (crow > N-1) crow = N-1;
    const float* src = outh + (size_t)crow*C2 + kh*16;
    #pragma unroll
    for (int s = 0; s < 4; s++){
        float4 a = *(const float4*)(src + s*32 + 0);
        float4 b = *(const float4*)(src + s*32 + 4);
        float4 c = *(const float4*)(src + s*32 + 8);
        float4 d = *(const float4*)(src + s*32 + 12);
        uint4 u0, u1;
        u0.x = pack2(a.x, a.y); u0.y = pack2(a.z, a.w);
        u0.z = pack2(b.x, b.y); u0.w = pack2(b.z, b.w);
        u1.x = pack2(c.x, c.y); u1.y = pack2(c.z, c.w);
        u1.z = pack2(d.x, d.y); u1.w = pack2(d.z, d.w);
        int d0 = ((s*8 + rt8)*64 + (kh*2)*16 + rr)*8;
        *(uint4*)&Af[d0]       = u0;
        *(uint4*)&Af[d0 + 128] = u1;
    }
    __syncthreads();

    f32x4 acc[4][2];
    #pragma unroll
    for (int i = 0; i < 4; i++)
        #pragma unroll
        for (int rt = 0; rt < 2; rt++)
            acc[i][rt] = (f32x4){0.f, 0.f, 0.f, 0.f};

    #pragma unroll
    for (int s = 0; s < 4; s++){
        bf16x8 af[2];
        #pragma unroll
        for (int rt = 0; rt < 2; rt++)
            af[rt] = __builtin_bit_cast(bf16x8, *(const uint4*)&Af[((s*8 + w*2 + rt)*64 + l)*8]);
        #pragma unroll
        for (int i = 0; i < 4; i++){
            bf16x8 bw = __builtin_bit_cast(bf16x8, *(const uint4*)&Wfa[((size_t)(s*4 + i)*64 + l)*8]);
            #pragma unroll
            for (int rt = 0; rt < 2; rt++)
                acc[i][rt] = __builtin_amdgcn_mfma_f32_16x16x32_bf16(bw, af[rt], acc[i][rt], 0, 0, 0);
        }
    }

    const int g = l >> 4;
    float4 abv[4], awv[4];
    #pragma unroll
    for (int i = 0; i < 4; i++){
        abv[i] = *(const float4*)&ab1[i*16 + g*4];
        awv[i] = *(const float4*)&aw2[i*16 + g*4];
    }
    float b2v = ab2[0];
    #pragma unroll
    for (int rt = 0; rt < 2; rt++){
        int node = n0 + (w*2 + rt)*16 + (l & 15);
        float part = 0.f;
        #pragma unroll
        for (int i = 0; i < 4; i++){
            float v0 = fmaxf(acc[i][rt][0] + abv[i].x, 0.f);
            float v1 = fmaxf(acc[i][rt][1] + abv[i].y, 0.f);
            float v2 = fmaxf(acc[i][rt][2] + abv[i].z, 0.f);
            float v3 = fmaxf(acc[i][rt][3] + abv[i].w, 0.f);
            part += v0*awv[i].x + v1*awv[i].y + v2*awv[i].z + v3*awv[i].w;
        }
        part += __shfl_xor(part, 16, 64);
        part += __shfl_xor(part, 32, 64);
        if (g == 0 && node < N)
            attn[node] = 1.f/(1.f + __expf(-(part + b2v)));
    }
}

extern "C" void kernel_launch(void* const* d_in, const int* in_sizes, int n_in,
                              void* d_out, int out_size, void* d_ws, size_t ws_size,
                              hipStream_t stream)
{
    const float* x    = (const float*)d_in[0];
    const int*   ei   = (const int*)  d_in[1];
    const float* pad  = (const float*)d_in[2];
    const float* W1   = (const float*)d_in[3];
    const float* as1  = (const float*)d_in[4];
    const float* ad1  = (const float*)d_in[5];
    const float* b1   = (const float*)d_in[6];
    const float* W2   = (const float*)d_in[7];
    const float* as2  = (const float*)d_in[8];
    const float* ad2  = (const float*)d_in[9];
    const float* b2   = (const float*)d_in[10];
    const float* aw1  = (const float*)d_in[11];
    const float* ab1  = (const float*)d_in[12];
    const float* aw2  = (const float*)d_in[13];
    const float* ab2  = (const float*)d_in[14];
    const float* gw   = (const float*)d_in[15];
    const float* gb   = (const float*)d_in[16];

    const int N = in_sizes[0] / IN_DIM;
    const int E = in_sizes[1] / 2;

    float* outh    = (float*)d_out;
    float* outattn = outh + (size_t)N*C2;

    char* w = (char*)d_ws;
    auto alloc = [&](size_t bytes)->char*{
        char* p = w;
        w += (bytes + 255) & ~(size_t)255;
        return p;
    };
    unsigned short* h1  = (unsigned short*)alloc((size_t)N*C1*2);
    unsigned short* x2  = (unsigned short*)alloc((size_t)N*C1*2);
    unsigned short* h2  = (unsigned short*)alloc((size_t)N*C2*2);
    float* als1 = (float*)alloc((size_t)N*4*4);
    float* ald1 = (float*)alloc((size_t)N*4*4);
    float* als2 = (float*)alloc((size_t)N*2*4);
    float* ald2 = (float*)alloc((size_t)N*2*4);
    int* deg    = (int*)alloc((size_t)N*4);
    int* cur    = (int*)alloc((size_t)N*4);
    int* rowptr = (int*)alloc((size_t)(N+1)*4);
    int* colx   = (int*)alloc((size_t)E*4);
    int* dstx   = (int*)alloc((size_t)E*4);
    int* part   = (int*)alloc(512*4);
    unsigned short* Wf1 = (unsigned short*)alloc((size_t)12*16*64*8*2);
    unsigned short* Wf2 = (unsigned short*)alloc((size_t)8*8*64*8*2);
    unsigned short* Wfa = (unsigned short*)alloc((size_t)4*4*64*8*2);
    float* c1v  = (float*)alloc(C1*4);
    float* gate = (float*)alloc(HID*4);

    // Lifetime-based aliases (no new footprint):
    float* ep1    = (float*)h2;                                   // E*4 floats
    float* den1   = (float*)((char*)h2 + (size_t)E*16);           // N*4 floats
    float* pSelf1 = (float*)((char*)h2 + (size_t)E*16 + (size_t)N*16);
    float* ep2    = (float*)x2;                                   // E*2 floats
    float* den2   = (float*)((char*)x2 + (size_t)E*8);            // N*2 floats
    float* pSelf2 = (float*)((char*)x2 + (size_t)E*8 + (size_t)N*8);

    const int nbN = (N + 255)/256;
    const int nbE = (E + 255)/256;
    const int nbW = (N + 3)/4;        // wave-per-node kernels
    const int nbG = (N + 127)/128;    // gemm / attn row blocks

    // weight swizzles + constants (independent of CSR)
    k_cvtW <<<(192+3)/4, 256, 0, stream>>>(W1, Wf1, C1, 16, 192);
    k_cvtW <<<(64+3)/4,  256, 0, stream>>>(W2, Wf2, C2, 8, 64);
    k_cvtW <<<(16+3)/4,  256, 0, stream>>>(aw1, Wfa, HID, 4, 16);
    k_prep <<<1, 256, 0, stream>>>(W1, pad, gw, gb, c1v, gate);

    // CSR by destination
    k_zero   <<<nbN, 256, 0, stream>>>(deg, cur, N);
    k_hist   <<<nbE, 256, 0, stream>>>(ei, deg, E);
    k_scan1  <<<nbN, 256, 0, stream>>>(deg, rowptr, part, N);
    k_scan2  <<<1, 512, 0, stream>>>(part, nbN);
    k_scan3  <<<nbN, 256, 0, stream>>>(rowptr, part, N, E);
    k_scatter<<<nbE, 256, 0, stream>>>(ei, rowptr, cur, colx, dstx, E);

    // ---- layer 1 ----
    k_gemm1_mfma<<<nbG, 256, 0, stream>>>(x, Wf1, c1v, as1, ad1, h1, als1, ald1, N);
    k_elogit<4><<<nbE, 256, 0, stream>>>(colx, dstx, als1, ald1, ep1, E);
    k_segsm<4> <<<(N*4 + 255)/256, 256, 0, stream>>>(rowptr, als1, ald1, ep1, den1, pSelf1, N*4);
    k_gat<4,4,1><<<nbW, 256, 0, stream>>>(h1, ep1, den1, pSelf1, rowptr, colx, b1,
                                          nullptr, x2, nullptr, N);

    // ---- layer 2 ----
    k_gemm2_mfma<<<nbG, 256, 0, stream>>>(x2, Wf2, as2, ad2, h2, als2, ald2, N);
    k_elogit<2><<<nbE, 256, 0, stream>>>(colx, dstx, als2, ald2, ep2, E);
    k_segsm<2> <<<(N*2 + 255)/256, 256, 0, stream>>>(rowptr, als2, ald2, ep2, den2, pSelf2, N*2);
    k_gat<2,2,2><<<nbW, 256, 0, stream>>>(h2, ep2, den2, pSelf2, rowptr, colx, b2,
                                          gate, nullptr, outh, N);

    // ---- attention-score MLP (MFMA) ----
    k_attn_mfma<<<nbG, 256, 0, stream>>>(outh, Wfa, ab1, aw2, ab2, outattn, N);
}

// Round 8
// 288.641 us; speedup vs baseline: 2.2214x; 1.0715x over previous
//
#include <hip/hip_runtime.h>
#include <hip/hip_bf16.h>
#include <stdint.h>

#define IN_DIM 384
#define HID 64
#define C1 256   // 4 heads * 64
#define C2 128   // 2 heads * 64

typedef unsigned int uint32;
typedef __bf16 bf16x8 __attribute__((ext_vector_type(8)));
typedef float f32x4 __attribute__((ext_vector_type(4)));

static __device__ __forceinline__ float bf2f(unsigned short u){
    return __uint_as_float(((uint32)u) << 16);
}
static __device__ __forceinline__ unsigned short f2bf(float x){
    uint32 u = __float_as_uint(x);
    return (unsigned short)((u + 0x7FFFu + ((u >> 16) & 1u)) >> 16);
}
static __device__ __forceinline__ uint32 pack2(float a, float b){
    return (uint32)f2bf(a) | ((uint32)f2bf(b) << 16);
}

// ---------------- CSR build ----------------
__global__ void k_zero(int* deg, int* cur, int N){
    int i = blockIdx.x*256 + threadIdx.x;
    if (i < N){ deg[i] = 0; cur[i] = 0; }
}
__global__ void k_hist(const int* __restrict__ ei, int* deg, int E){
    int i = blockIdx.x*256 + threadIdx.x;
    if (i < E) atomicAdd(&deg[ei[E + i]], 1);
}
__global__ void k_scan1(const int* __restrict__ deg, int* rowptr, int* part, int N){
    __shared__ int s[256];
    int tid = threadIdx.x;
    int i = blockIdx.x*256 + tid;
    int v = (i < N) ? deg[i] : 0;
    s[tid] = v; __syncthreads();
    for (int off = 1; off < 256; off <<= 1){
        int t = (tid >= off) ? s[tid - off] : 0;
        __syncthreads();
        s[tid] += t;
        __syncthreads();
    }
    if (i < N) rowptr[i] = s[tid] - v;
    if (tid == 255) part[blockIdx.x] = s[tid];
}
__global__ void k_scan2(int* part, int nb){
    __shared__ int s[512];
    int tid = threadIdx.x;
    int v = (tid < nb) ? part[tid] : 0;
    s[tid] = v; __syncthreads();
    for (int off = 1; off < 512; off <<= 1){
        int t = (tid >= off) ? s[tid - off] : 0;
        __syncthreads();
        s[tid] += t;
        __syncthreads();
    }
    if (tid < nb) part[tid] = s[tid] - v;
}
__global__ void k_scan3(int* rowptr, const int* __restrict__ part, int N, int E){
    int i = blockIdx.x*256 + threadIdx.x;
    if (i < N) rowptr[i] += part[blockIdx.x];
    if (i == 0) rowptr[N] = E;
}
__global__ void k_scatter(const int* __restrict__ ei, const int* __restrict__ rowptr,
                          int* cur, int* colx, int* dstx, int E){
    int i = blockIdx.x*256 + threadIdx.x;
    if (i < E){
        int d = ei[E + i];
        int pos = atomicAdd(&cur[d], 1);
        int p = rowptr[d] + pos;
        colx[p] = ei[i];
        dstx[p] = d;
    }
}

// ---------------- weight pre-swizzle: contiguous-k fragment order ----------------
// Wf[unit = s*ntiles+ct][lane l][j] = W[k = s*32 + 8*(l>>4) + j][ct*16 + (l&15)]
__global__ __launch_bounds__(256) void k_cvtW(const float* __restrict__ W,
        unsigned short* __restrict__ Wf, int ncol, int ntiles, int nunits){
    int unit = blockIdx.x*4 + (threadIdx.x >> 6);
    if (unit >= nunits) return;
    int l = threadIdx.x & 63;
    int s = unit / ntiles, ct = unit % ntiles;
    int col = ct*16 + (l & 15);
    int g = l >> 4;
    unsigned short o[8];
    #pragma unroll
    for (int j = 0; j < 8; j++){
        int k = s*32 + g*8 + j;
        o[j] = f2bf(W[(size_t)k*ncol + col]);
    }
    ushort4* dst = (ushort4*)&Wf[((size_t)unit*64 + l)*8];
    dst[0] = make_ushort4(o[0], o[1], o[2], o[3]);
    dst[1] = make_ushort4(o[4], o[5], o[6], o[7]);
}

// ---------------- constant precompute: pad bias, emotion gate ----------
__global__ __launch_bounds__(256) void k_prep(const float* __restrict__ W1,
        const float* __restrict__ pad, const float* __restrict__ gw, const float* __restrict__ gb,
        float* __restrict__ c1v, float* __restrict__ gate){
    int tid = threadIdx.x;
    c1v[tid] = pad[0]*W1[(size_t)(IN_DIM+0)*C1 + tid]
             + pad[1]*W1[(size_t)(IN_DIM+1)*C1 + tid]
             + pad[2]*W1[(size_t)(IN_DIM+2)*C1 + tid];
    if (tid < HID){
        float g = pad[0]*gw[0*HID + tid] + pad[1]*gw[1*HID + tid] + pad[2]*gw[2*HID + tid] + gb[tid];
        gate[tid] = 1.f/(1.f + __expf(-g));
    }
}

// ---------------- GEMM1 (MFMA): h1 = [x|pad]@W1 + fused al1 epilogue ----------------
// 64 rows x 256 cols per block, 4 waves, wave w -> head w; acc[4][4]=64 AGPR (occupancy!)
__global__ __launch_bounds__(256) void k_gemm1_mfma(const float* __restrict__ x,
        const unsigned short* __restrict__ Wf, const float* __restrict__ c1v,
        const float* __restrict__ as1, const float* __restrict__ ad1,
        unsigned short* __restrict__ h1, float* __restrict__ als, float* __restrict__ ald, int N)
{
    __shared__ unsigned short Af[2][4*64*8];   // 2 x 4KB
    const int tid = threadIdx.x;
    const int l   = tid & 63;
    const int w   = tid >> 6;
    const int n0  = blockIdx.x * 64;

    // staging: thread covers row tid>>2, k-chunk (tid&3)*8 of the 32-wide step (32B load)
    const int sr  = tid >> 2;
    const int kc  = tid & 3;
    const int d0  = ((sr >> 4)*64 + kc*16 + (sr & 15))*8;
    int crow = n0 + sr; if (crow > N-1) crow = N-1;
    const float* xrow = x + (size_t)crow*IN_DIM + kc*8;

    f32x4 acc[4][4];
    #pragma unroll
    for (int i = 0; i < 4; i++)
        #pragma unroll
        for (int rt = 0; rt < 4; rt++)
            acc[i][rt] = (f32x4){0.f, 0.f, 0.f, 0.f};

    float4 ra, rb;
    uint4 wcur[4], wnxt[4];

    ra = *(const float4*)(xrow + 0); rb = *(const float4*)(xrow + 4);
    {
        uint4 u;
        u.x = pack2(ra.x, ra.y); u.y = pack2(ra.z, ra.w);
        u.z = pack2(rb.x, rb.y); u.w = pack2(rb.z, rb.w);
        *(uint4*)&Af[0][d0] = u;
    }
    {
        const unsigned short* p = Wf + ((size_t)(w*4)*64 + l)*8;
        #pragma unroll
        for (int i = 0; i < 4; i++) wcur[i] = *(const uint4*)(p + (size_t)i*512);
    }
    __syncthreads();

    for (int s = 0; s < 12; ++s){
        if (s < 11){
            const float* src = xrow + (s+1)*32;
            ra = *(const float4*)(src + 0); rb = *(const float4*)(src + 4);
            const unsigned short* p = Wf + ((size_t)((s+1)*16 + w*4)*64 + l)*8;
            #pragma unroll
            for (int i = 0; i < 4; i++) wnxt[i] = *(const uint4*)(p + (size_t)i*512);
        }
        bf16x8 af[4];
        #pragma unroll
        for (int rt = 0; rt < 4; rt++)
            af[rt] = __builtin_bit_cast(bf16x8, *(const uint4*)&Af[s&1][(rt*64 + l)*8]);
        #pragma unroll
        for (int i = 0; i < 4; i++){
            bf16x8 bw = __builtin_bit_cast(bf16x8, wcur[i]);
            #pragma unroll
            for (int rt = 0; rt < 4; rt++)
                acc[i][rt] = __builtin_amdgcn_mfma_f32_16x16x32_bf16(bw, af[rt], acc[i][rt], 0, 0, 0);
        }
        if (s < 11){
            uint4 u;
            u.x = pack2(ra.x, ra.y); u.y = pack2(ra.z, ra.w);
            u.z = pack2(rb.x, rb.y); u.w = pack2(rb.z, rb.w);
            *(uint4*)&Af[(s+1)&1][d0] = u;
            __syncthreads();
            #pragma unroll
            for (int i = 0; i < 4; i++) wcur[i] = wnxt[i];
        }
    }

    const int g = l >> 4;
    float4 cvv[4], av[4], dv[4];
    #pragma unroll
    for (int i = 0; i < 4; i++){
        int cl = i*16 + g*4;
        cvv[i] = *(const float4*)&c1v[w*64 + cl];
        av[i]  = *(const float4*)&as1[w*64 + cl];
        dv[i]  = *(const float4*)&ad1[w*64 + cl];
    }
    #pragma unroll
    for (int rt = 0; rt < 4; rt++){
        int node = n0 + rt*16 + (l & 15);
        bool ok = node < N;
        float ps = 0.f, pd = 0.f;
        #pragma unroll
        for (int i = 0; i < 4; i++){
            float h0 = acc[i][rt][0] + cvv[i].x;
            float h1v = acc[i][rt][1] + cvv[i].y;
            float h2v = acc[i][rt][2] + cvv[i].z;
            float h3v = acc[i][rt][3] + cvv[i].w;
            ps += h0*av[i].x + h1v*av[i].y + h2v*av[i].z + h3v*av[i].w;
            pd += h0*dv[i].x + h1v*dv[i].y + h2v*dv[i].z + h3v*dv[i].w;
            if (ok){
                ushort4 o = make_ushort4(f2bf(h0), f2bf(h1v), f2bf(h2v), f2bf(h3v));
                *(ushort4*)&h1[(size_t)node*C1 + w*64 + i*16 + g*4] = o;
            }
        }
        ps += __shfl_xor(ps, 16, 64); ps += __shfl_xor(ps, 32, 64);
        pd += __shfl_xor(pd, 16, 64); pd += __shfl_xor(pd, 32, 64);
        if (ok && g == 0){
            als[(size_t)node*4 + w] = ps;
            ald[(size_t)node*4 + w] = pd;
        }
    }
}

// ---------------- GEMM2 (MFMA): h2 = x2 @ W2 + fused al2 epilogue ----------------
// 64 rows x 128 cols, 4 waves: wc = w&1 (head), wr = w>>1 (32-row half); acc[4][2]=32 AGPR
__global__ __launch_bounds__(256) void k_gemm2_mfma(const unsigned short* __restrict__ x2,
        const unsigned short* __restrict__ Wf,
        const float* __restrict__ as2, const float* __restrict__ ad2,
        unsigned short* __restrict__ h2, float* __restrict__ als, float* __restrict__ ald, int N)
{
    __shared__ unsigned short Af[2][4*64*8];   // 2 x 4KB
    const int tid = threadIdx.x;
    const int l   = tid & 63;
    const int w   = tid >> 6;
    const int wr  = w >> 1, wc = w & 1;
    const int n0  = blockIdx.x * 64;

    const int sr  = tid >> 2;
    const int kc  = tid & 3;
    const int d0  = ((sr >> 4)*64 + kc*16 + (sr & 15))*8;
    int crow = n0 + sr; if (crow > N-1) crow = N-1;
    const unsigned short* xrow = x2 + (size_t)crow*C1 + kc*8;

    f32x4 acc[4][2];
    #pragma unroll
    for (int i = 0; i < 4; i++)
        #pragma unroll
        for (int rt = 0; rt < 2; rt++)
            acc[i][rt] = (f32x4){0.f, 0.f, 0.f, 0.f};

    uint4 p0, wcur[4], wnxt[4];
    p0 = *(const uint4*)(xrow);
    *(uint4*)&Af[0][d0] = p0;
    {
        const unsigned short* p = Wf + ((size_t)(wc*4)*64 + l)*8;
        #pragma unroll
        for (int i = 0; i < 4; i++) wcur[i] = *(const uint4*)(p + (size_t)i*512);
    }
    __syncthreads();

    for (int s = 0; s < 8; ++s){
        if (s < 7){
            p0 = *(const uint4*)(xrow + (s+1)*32);
            const unsigned short* p = Wf + ((size_t)((s+1)*8 + wc*4)*64 + l)*8;
            #pragma unroll
            for (int i = 0; i < 4; i++) wnxt[i] = *(const uint4*)(p + (size_t)i*512);
        }
        bf16x8 af[2];
        #pragma unroll
        for (int rt = 0; rt < 2; rt++)
            af[rt] = __builtin_bit_cast(bf16x8, *(const uint4*)&Af[s&1][((wr*2 + rt)*64 + l)*8]);
        #pragma unroll
        for (int i = 0; i < 4; i++){
            bf16x8 bw = __builtin_bit_cast(bf16x8, wcur[i]);
            #pragma unroll
            for (int rt = 0; rt < 2; rt++)
                acc[i][rt] = __builtin_amdgcn_mfma_f32_16x16x32_bf16(bw, af[rt], acc[i][rt], 0, 0, 0);
        }
        if (s < 7){
            *(uint4*)&Af[(s+1)&1][d0] = p0;
            __syncthreads();
            #pragma unroll
            for (int i = 0; i < 4; i++) wcur[i] = wnxt[i];
        }
    }

    const int g = l >> 4;
    float4 av[4], dv[4];
    #pragma unroll
    for (int i = 0; i < 4; i++){
        int cl = i*16 + g*4;
        av[i] = *(const float4*)&as2[wc*64 + cl];
        dv[i] = *(const float4*)&ad2[wc*64 + cl];
    }
    #pragma unroll
    for (int rt = 0; rt < 2; rt++){
        int node = n0 + wr*32 + rt*16 + (l & 15);
        bool ok = node < N;
        float ps = 0.f, pd = 0.f;
        #pragma unroll
        for (int i = 0; i < 4; i++){
            float h0 = acc[i][rt][0], h1v = acc[i][rt][1];
            float h2v = acc[i][rt][2], h3v = acc[i][rt][3];
            ps += h0*av[i].x + h1v*av[i].y + h2v*av[i].z + h3v*av[i].w;
            pd += h0*dv[i].x + h1v*dv[i].y + h2v*dv[i].z + h3v*dv[i].w;
            if (ok){
                ushort4 o = make_ushort4(f2bf(h0), f2bf(h1v), f2bf(h2v), f2bf(h3v));
                *(ushort4*)&h2[(size_t)node*C2 + wc*64 + i*16 + g*4] = o;
            }
        }
        ps += __shfl_xor(ps, 16, 64); ps += __shfl_xor(ps, 32, 64);
        pd += __shfl_xor(pd, 16, 64); pd += __shfl_xor(pd, 32, 64);
        if (ok && g == 0){
            als[(size_t)node*2 + wc] = ps;
            ald[(size_t)node*2 + wc] = pd;
        }
    }
}

// ---------------- A: edge-parallel logits e = leaky(als[src]+ald[dst]) ----------------
template<int H>
__global__ __launch_bounds__(256) void k_elogit(const int* __restrict__ colx,
        const int* __restrict__ dstx, const float* __restrict__ als,
        const float* __restrict__ ald, float* __restrict__ ep, int E)
{
    int i = blockIdx.x*256 + threadIdx.x;
    if (i >= E) return;
    int s = colx[i], d = dstx[i];
    if constexpr (H == 4){
        float4 a = *(const float4*)&als[(size_t)s*4];
        float4 b = *(const float4*)&ald[(size_t)d*4];
        float4 e;
        e.x = a.x + b.x; e.x = fmaxf(e.x, 0.2f*e.x);
        e.y = a.y + b.y; e.y = fmaxf(e.y, 0.2f*e.y);
        e.z = a.z + b.z; e.z = fmaxf(e.z, 0.2f*e.z);
        e.w = a.w + b.w; e.w = fmaxf(e.w, 0.2f*e.w);
        *(float4*)&ep[(size_t)i*4] = e;
    } else {
        float2 a = *(const float2*)&als[(size_t)s*2];
        float2 b = *(const float2*)&ald[(size_t)d*2];
        float2 e;
        e.x = a.x + b.x; e.x = fmaxf(e.x, 0.2f*e.x);
        e.y = a.y + b.y; e.y = fmaxf(e.y, 0.2f*e.y);
        *(float2*)&ep[(size_t)i*2] = e;
    }
}

// ---------------- B: thread per (node,head) segment softmax; ep <- p (in place) -------
template<int H>
__global__ __launch_bounds__(256) void k_segsm(const int* __restrict__ rowptr,
        const float* __restrict__ als, const float* __restrict__ ald,
        float* __restrict__ ep, float* __restrict__ den, float* __restrict__ pSelf, int NH)
{
    int t = blockIdx.x*256 + threadIdx.x;
    if (t >= NH) return;
    int node = t / H;
    int head = t - node*H;
    int base = rowptr[node];
    int cnt  = rowptr[node+1] - base;
    float es = als[t] + ald[t];
    es = fmaxf(es, 0.2f*es);
    float m = es;
    for (int j = 0; j < cnt; j++)
        m = fmaxf(m, ep[(size_t)(base + j)*H + head]);
    float ps = __expf(es - m);
    float dn = ps;
    for (int j = 0; j < cnt; j++){
        size_t idx = (size_t)(base + j)*H + head;
        float p = __expf(ep[idx] - m);
        ep[idx] = p;
        dn += p;
    }
    den[t]   = dn;
    pSelf[t] = ps;
}

// ---------------- C: wave-per-node weighted gather-sum (no softmax in loop) ----------
template<int H, int CPL, int LAYER>
__global__ __launch_bounds__(256) void k_gat(const unsigned short* __restrict__ hlin,
        const float* __restrict__ ep, const float* __restrict__ den, const float* __restrict__ pSelf,
        const int* __restrict__ rowptr, const int* __restrict__ colx,
        const float* __restrict__ bias, const float* __restrict__ gate,
        unsigned short* __restrict__ out_bf, float* __restrict__ out_f, int N)
{
    constexpr int C = H*64;
    constexpr uint32 RB = C*2;               // bf16 row bytes
    int lane = threadIdx.x & 63, wid = threadIdx.x >> 6;
    int n = blockIdx.x*4 + wid;
    if (n >= N) return;
    const int c0 = lane*CPL;
    const int head = c0 >> 6;
    const int base = rowptr[n];
    const int cnt  = rowptr[n+1] - base;
    const char* hbase = (const char*)hlin + (uint32)c0*2;

    float acc[CPL];
    {
        float psf = pSelf[(uint32)n*H + head];
        if constexpr (CPL == 4){
            ushort4 v = *(const ushort4*)(hbase + (size_t)(uint32)n*RB);
            acc[0] = psf*bf2f(v.x); acc[1] = psf*bf2f(v.y);
            acc[2] = psf*bf2f(v.z); acc[3] = psf*bf2f(v.w);
        } else {
            uint32 v = *(const uint32*)(hbase + (size_t)(uint32)n*RB);
            acc[0] = psf*bf2f((unsigned short)(v & 0xffff));
            acc[1] = psf*bf2f((unsigned short)(v >> 16));
        }
    }
    for (int i = 0; i < cnt; i += 4){
        int idx[4], sk[4];
        #pragma unroll
        for (int k = 0; k < 4; k++){
            int ii = i + k; if (ii > cnt-1) ii = cnt-1;
            idx[k] = base + ii;
        }
        #pragma unroll
        for (int k = 0; k < 4; k++) sk[k] = colx[idx[k]];
        float pk[4];
        #pragma unroll
        for (int k = 0; k < 4; k++){
            float pv = ep[(size_t)(uint32)idx[k]*H + head];   // position-indexed: no colx dep
            pk[k] = (i + k < cnt) ? pv : 0.f;
        }
        if constexpr (CPL == 4){
            ushort4 h4[4];
            #pragma unroll
            for (int k = 0; k < 4; k++) h4[k] = *(const ushort4*)(hbase + (size_t)(uint32)sk[k]*RB);
            #pragma unroll
            for (int k = 0; k < 4; k++){
                acc[0] += pk[k]*bf2f(h4[k].x);
                acc[1] += pk[k]*bf2f(h4[k].y);
                acc[2] += pk[k]*bf2f(h4[k].z);
                acc[3] += pk[k]*bf2f(h4[k].w);
            }
        } else {
            uint32 h2v[4];
            #pragma unroll
            for (int k = 0; k < 4; k++) h2v[k] = *(const uint32*)(hbase + (size_t)(uint32)sk[k]*RB);
            #pragma unroll
            for (int k = 0; k < 4; k++){
                acc[0] += pk[k]*bf2f((unsigned short)(h2v[k] & 0xffff));
                acc[1] += pk[k]*bf2f((unsigned short)(h2v[k] >> 16));
            }
        }
    }

    float inv = 1.f/(den[(uint32)n*H + head] + 1e-16f);
    if constexpr (LAYER == 1){
        unsigned short o[CPL];
        #pragma unroll
        for (int j = 0; j < CPL; j++){
            float r = acc[j]*inv + bias[c0 + j];
            r = (r > 0.f) ? r : (__expf(r) - 1.f);   // elu
            o[j] = f2bf(r);
        }
        if constexpr (CPL == 4){
            ushort4 ov; ov.x = o[0]; ov.y = o[1]; ov.z = o[2]; ov.w = o[3];
            *(ushort4*)&out_bf[(size_t)n*C + c0] = ov;
        }
    } else {
        float o[CPL];
        #pragma unroll
        for (int j = 0; j < CPL; j++){
            float r = acc[j]*inv + bias[c0 + j];
            r = (r > 0.f) ? r : (__expf(r) - 1.f);   // elu
            o[j] = r*gate[(c0 + j) & 63];
        }
        if constexpr (CPL == 2){
            *(float2*)&out_f[(size_t)n*C + c0] = make_float2(o[0], o[1]);
        }
    }
}

// ---------------- attn MLP via MFMA: attn = sigmoid(relu(outh@aw1+ab1)@aw2+ab2) -------
__global__ __launch_bounds__(256) void k_attn_mfma(const float* __restrict__ outh,
        const unsigned short* __restrict__ Wfa, const float* __restrict__ ab1,
        const float* __restrict__ aw2, const float* __restrict__ ab2,
        float* __restrict__ attn, int N)
{
    __shared__ unsigned short Af[4*8*64*8];   // 32 KB: [kstep s][rowtile rt][lane][8]
    const int tid = threadIdx.x;
    const int l   = tid & 63;
    const int w   = tid >> 6;
    const int n0  = blockIdx.x * 128;

    const int r  = tid >> 1;
    const int kh = tid & 1;
    const int rt8 = r >> 4, rr = r & 15;
    int crow = n0 + r; if (crow > N-1) crow = N-1;
    const float* src = outh + (size_t)crow*C2 + kh*16;
    #pragma unroll
    for (int s = 0; s < 4; s++){
        float4 a = *(const float4*)(src + s*32 + 0);
        float4 b = *(const float4*)(src + s*32 + 4);
        float4 c = *(const float4*)(src + s*32 + 8);
        float4 d = *(const float4*)(src + s*32 + 12);
        uint4 u0, u1;
        u0.x = pack2(a.x, a.y); u0.y = pack2(a.z, a.w);
        u0.z = pack2(b.x, b.y); u0.w = pack2(b.z, b.w);
        u1.x = pack2(c.x, c.y); u1.y = pack2(c.z, c.w);
        u1.z = pack2(d.x, d.y); u1.w = pack2(d.z, d.w);
        int d0 = ((s*8 + rt8)*64 + (kh*2)*16 + rr)*8;
        *(uint4*)&Af[d0]       = u0;
        *(uint4*)&Af[d0 + 128] = u1;
    }
    __syncthreads();

    f32x4 acc[4][2];
    #pragma unroll
    for (int i = 0; i < 4; i++)
        #pragma unroll
        for (int rt = 0; rt < 2; rt++)
            acc[i][rt] = (f32x4){0.f, 0.f, 0.f, 0.f};

    #pragma unroll
    for (int s = 0; s < 4; s++){
        bf16x8 af[2];
        #pragma unroll
        for (int rt = 0; rt < 2; rt++)
            af[rt] = __builtin_bit_cast(bf16x8, *(const uint4*)&Af[((s*8 + w*2 + rt)*64 + l)*8]);
        #pragma unroll
        for (int i = 0; i < 4; i++){
            bf16x8 bw = __builtin_bit_cast(bf16x8, *(const uint4*)&Wfa[((size_t)(s*4 + i)*64 + l)*8]);
            #pragma unroll
            for (int rt = 0; rt < 2; rt++)
                acc[i][rt] = __builtin_amdgcn_mfma_f32_16x16x32_bf16(bw, af[rt], acc[i][rt], 0, 0, 0);
        }
    }

    const int g = l >> 4;
    float4 abv[4], awv[4];
    #pragma unroll
    for (int i = 0; i < 4; i++){
        abv[i] = *(const float4*)&ab1[i*16 + g*4];
        awv[i] = *(const float4*)&aw2[i*16 + g*4];
    }
    float b2v = ab2[0];
    #pragma unroll
    for (int rt = 0; rt < 2; rt++){
        int node = n0 + (w*2 + rt)*16 + (l & 15);
        float part = 0.f;
        #pragma unroll
        for (int i = 0; i < 4; i++){
            float v0 = fmaxf(acc[i][rt][0] + abv[i].x, 0.f);
            float v1 = fmaxf(acc[i][rt][1] + abv[i].y, 0.f);
            float v2 = fmaxf(acc[i][rt][2] + abv[i].z, 0.f);
            float v3 = fmaxf(acc[i][rt][3] + abv[i].w, 0.f);
            part += v0*awv[i].x + v1*awv[i].y + v2*awv[i].z + v3*awv[i].w;
        }
        part += __shfl_xor(part, 16, 64);
        part += __shfl_xor(part, 32, 64);
        if (g == 0 && node < N)
            attn[node] = 1.f/(1.f + __expf(-(part + b2v)));
    }
}

extern "C" void kernel_launch(void* const* d_in, const int* in_sizes, int n_in,
                              void* d_out, int out_size, void* d_ws, size_t ws_size,
                              hipStream_t stream)
{
    const float* x    = (const float*)d_in[0];
    const int*   ei   = (const int*)  d_in[1];
    const float* pad  = (const float*)d_in[2];
    const float* W1   = (const float*)d_in[3];
    const float* as1  = (const float*)d_in[4];
    const float* ad1  = (const float*)d_in[5];
    const float* b1   = (const float*)d_in[6];
    const float* W2   = (const float*)d_in[7];
    const float* as2  = (const float*)d_in[8];
    const float* ad2  = (const float*)d_in[9];
    const float* b2   = (const float*)d_in[10];
    const float* aw1  = (const float*)d_in[11];
    const float* ab1  = (const float*)d_in[12];
    const float* aw2  = (const float*)d_in[13];
    const float* ab2  = (const float*)d_in[14];
    const float* gw   = (const float*)d_in[15];
    const float* gb   = (const float*)d_in[16];

    const int N = in_sizes[0] / IN_DIM;
    const int E = in_sizes[1] / 2;

    float* outh    = (float*)d_out;
    float* outattn = outh + (size_t)N*C2;

    char* w = (char*)d_ws;
    auto alloc = [&](size_t bytes)->char*{
        char* p = w;
        w += (bytes + 255) & ~(size_t)255;
        return p;
    };
    unsigned short* h1  = (unsigned short*)alloc((size_t)N*C1*2);
    unsigned short* x2  = (unsigned short*)alloc((size_t)N*C1*2);
    unsigned short* h2  = (unsigned short*)alloc((size_t)N*C2*2);
    float* als1 = (float*)alloc((size_t)N*4*4);
    float* ald1 = (float*)alloc((size_t)N*4*4);
    float* als2 = (float*)alloc((size_t)N*2*4);
    float* ald2 = (float*)alloc((size_t)N*2*4);
    int* deg    = (int*)alloc((size_t)N*4);
    int* cur    = (int*)alloc((size_t)N*4);
    int* rowptr = (int*)alloc((size_t)(N+1)*4);
    int* colx   = (int*)alloc((size_t)E*4);
    int* dstx   = (int*)alloc((size_t)E*4);
    int* part   = (int*)alloc(512*4);
    unsigned short* Wf1 = (unsigned short*)alloc((size_t)12*16*64*8*2);
    unsigned short* Wf2 = (unsigned short*)alloc((size_t)8*8*64*8*2);
    unsigned short* Wfa = (unsigned short*)alloc((size_t)4*4*64*8*2);
    float* c1v  = (float*)alloc(C1*4);
    float* gate = (float*)alloc(HID*4);

    // Lifetime-based aliases (no new footprint):
    float* ep1    = (float*)h2;                                   // E*4 floats
    float* den1   = (float*)((char*)h2 + (size_t)E*16);           // N*4 floats
    float* pSelf1 = (float*)((char*)h2 + (size_t)E*16 + (size_t)N*16);
    float* ep2    = (float*)x2;                                   // E*2 floats
    float* den2   = (float*)((char*)x2 + (size_t)E*8);            // N*2 floats
    float* pSelf2 = (float*)((char*)x2 + (size_t)E*8 + (size_t)N*8);

    const int nbN = (N + 255)/256;
    const int nbE = (E + 255)/256;
    const int nbW = (N + 3)/4;        // wave-per-node kernels
    const int nbG = (N + 63)/64;      // gemm row blocks (64-row tiles)
    const int nbA = (N + 127)/128;    // attn-MLP row blocks

    // weight swizzles + constants (independent of CSR)
    k_cvtW <<<(192+3)/4, 256, 0, stream>>>(W1, Wf1, C1, 16, 192);
    k_cvtW <<<(64+3)/4,  256, 0, stream>>>(W2, Wf2, C2, 8, 64);
    k_cvtW <<<(16+3)/4,  256, 0, stream>>>(aw1, Wfa, HID, 4, 16);
    k_prep <<<1, 256, 0, stream>>>(W1, pad, gw, gb, c1v, gate);

    // CSR by destination
    k_zero   <<<nbN, 256, 0, stream>>>(deg, cur, N);
    k_hist   <<<nbE, 256, 0, stream>>>(ei, deg, E);
    k_scan1  <<<nbN, 256, 0, stream>>>(deg, rowptr, part, N);
    k_scan2  <<<1, 512, 0, stream>>>(part, nbN);
    k_scan3  <<<nbN, 256, 0, stream>>>(rowptr, part, N, E);
    k_scatter<<<nbE, 256, 0, stream>>>(ei, rowptr, cur, colx, dstx, E);

    // ---- layer 1 ----
    k_gemm1_mfma<<<nbG, 256, 0, stream>>>(x, Wf1, c1v, as1, ad1, h1, als1, ald1, N);
    k_elogit<4><<<nbE, 256, 0, stream>>>(colx, dstx, als1, ald1, ep1, E);
    k_segsm<4> <<<(N*4 + 255)/256, 256, 0, stream>>>(rowptr, als1, ald1, ep1, den1, pSelf1, N*4);
    k_gat<4,4,1><<<nbW, 256, 0, stream>>>(h1, ep1, den1, pSelf1, rowptr, colx, b1,
                                          nullptr, x2, nullptr, N);

    // ---- layer 2 ----
    k_gemm2_mfma<<<nbG, 256, 0, stream>>>(x2, Wf2, as2, ad2, h2, als2, ald2, N);
    k_elogit<2><<<nbE, 256, 0, stream>>>(colx, dstx, als2, ald2, ep2, E);
    k_segsm<2> <<<(N*2 + 255)/256, 256, 0, stream>>>(rowptr, als2, ald2, ep2, den2, pSelf2, N*2);
    k_gat<2,2,2><<<nbW, 256, 0, stream>>>(h2, ep2, den2, pSelf2, rowptr, colx, b2,
                                          gate, nullptr, outh, N);

    // ---- attention-score MLP (MFMA) ----
    k_attn_mfma<<<nbA, 256, 0, stream>>>(outh, Wfa, ab1, aw2, ab2, outattn, N);
}

// Round 9
// 283.205 us; speedup vs baseline: 2.2640x; 1.0192x over previous
//
#include <hip/hip_runtime.h>
#include <hip/hip_bf16.h>
#include <stdint.h>

#define IN_DIM 384
#define HID 64
#define C1 256   // 4 heads * 64
#define C2 128   // 2 heads * 64

typedef unsigned int uint32;
typedef __bf16 bf16x8 __attribute__((ext_vector_type(8)));
typedef float f32x4 __attribute__((ext_vector_type(4)));

static __device__ __forceinline__ float bf2f(unsigned short u){
    return __uint_as_float(((uint32)u) << 16);
}
static __device__ __forceinline__ unsigned short f2bf(float x){
    uint32 u = __float_as_uint(x);
    return (unsigned short)((u + 0x7FFFu + ((u >> 16) & 1u)) >> 16);
}
static __device__ __forceinline__ uint32 pack2(float a, float b){
    return (uint32)f2bf(a) | ((uint32)f2bf(b) << 16);
}

// ---------------- CSR build ----------------
__global__ void k_zero(int* deg, int* cur, int N){
    int i = blockIdx.x*256 + threadIdx.x;
    if (i < N){ deg[i] = 0; cur[i] = 0; }
}
__global__ void k_hist(const int* __restrict__ ei, int* deg, int E){
    int i = blockIdx.x*256 + threadIdx.x;
    if (i < E) atomicAdd(&deg[ei[E + i]], 1);
}
__global__ void k_scan1(const int* __restrict__ deg, int* rowptr, int* part, int N){
    __shared__ int s[256];
    int tid = threadIdx.x;
    int i = blockIdx.x*256 + tid;
    int v = (i < N) ? deg[i] : 0;
    s[tid] = v; __syncthreads();
    for (int off = 1; off < 256; off <<= 1){
        int t = (tid >= off) ? s[tid - off] : 0;
        __syncthreads();
        s[tid] += t;
        __syncthreads();
    }
    if (i < N) rowptr[i] = s[tid] - v;
    if (tid == 255) part[blockIdx.x] = s[tid];
}
__global__ void k_scan2(int* part, int nb){
    __shared__ int s[512];
    int tid = threadIdx.x;
    int v = (tid < nb) ? part[tid] : 0;
    s[tid] = v; __syncthreads();
    for (int off = 1; off < 512; off <<= 1){
        int t = (tid >= off) ? s[tid - off] : 0;
        __syncthreads();
        s[tid] += t;
        __syncthreads();
    }
    if (tid < nb) part[tid] = s[tid] - v;
}
__global__ void k_scan3(int* rowptr, const int* __restrict__ part, int N, int E){
    int i = blockIdx.x*256 + threadIdx.x;
    if (i < N) rowptr[i] += part[blockIdx.x];
    if (i == 0) rowptr[N] = E;
}
__global__ void k_scatter(const int* __restrict__ ei, const int* __restrict__ rowptr,
                          int* cur, int* colx, int* dstx, int E){
    int i = blockIdx.x*256 + threadIdx.x;
    if (i < E){
        int d = ei[E + i];
        int pos = atomicAdd(&cur[d], 1);
        int p = rowptr[d] + pos;
        colx[p] = ei[i];
        dstx[p] = d;
    }
}

// ---------------- weight pre-swizzle: contiguous-k fragment order ----------------
// Wf[unit = ku*ntiles+ct][lane l][j] = W[k = ku*32 + 8*(l>>4) + j][ct*16 + (l&15)]
__global__ __launch_bounds__(256) void k_cvtW(const float* __restrict__ W,
        unsigned short* __restrict__ Wf, int ncol, int ntiles, int nunits){
    int unit = blockIdx.x*4 + (threadIdx.x >> 6);
    if (unit >= nunits) return;
    int l = threadIdx.x & 63;
    int s = unit / ntiles, ct = unit % ntiles;
    int col = ct*16 + (l & 15);
    int g = l >> 4;
    unsigned short o[8];
    #pragma unroll
    for (int j = 0; j < 8; j++){
        int k = s*32 + g*8 + j;
        o[j] = f2bf(W[(size_t)k*ncol + col]);
    }
    ushort4* dst = (ushort4*)&Wf[((size_t)unit*64 + l)*8];
    dst[0] = make_ushort4(o[0], o[1], o[2], o[3]);
    dst[1] = make_ushort4(o[4], o[5], o[6], o[7]);
}

// ---------------- constant precompute: pad bias, emotion gate ----------
__global__ __launch_bounds__(256) void k_prep(const float* __restrict__ W1,
        const float* __restrict__ pad, const float* __restrict__ gw, const float* __restrict__ gb,
        float* __restrict__ c1v, float* __restrict__ gate){
    int tid = threadIdx.x;
    c1v[tid] = pad[0]*W1[(size_t)(IN_DIM+0)*C1 + tid]
             + pad[1]*W1[(size_t)(IN_DIM+1)*C1 + tid]
             + pad[2]*W1[(size_t)(IN_DIM+2)*C1 + tid];
    if (tid < HID){
        float g = pad[0]*gw[0*HID + tid] + pad[1]*gw[1*HID + tid] + pad[2]*gw[2*HID + tid] + gb[tid];
        gate[tid] = 1.f/(1.f + __expf(-g));
    }
}

// ---------------- GEMM1 (MFMA): h1 = [x|pad]@W1 + fused al1 epilogue ----------------
// 64 rows x 256 cols per block, 4 waves (wave w = head w).
// K staged 96 floats/barrier (3 MFMA k-units): 6 global float4 in flight per thread,
// 48 MFMA/wave between barriers, 4 barriers total. LDS dbuf 2 x 12 KB.
__global__ __launch_bounds__(256) void k_gemm1_mfma(const float* __restrict__ x,
        const unsigned short* __restrict__ Wf, const float* __restrict__ c1v,
        const float* __restrict__ as1, const float* __restrict__ ad1,
        unsigned short* __restrict__ h1, float* __restrict__ als, float* __restrict__ ald, int N)
{
    __shared__ unsigned short Af[2][12*64*8];   // 2 x 12 KB; [u*4+rt][lane][8]
    const int tid = threadIdx.x;
    const int l   = tid & 63;
    const int w   = tid >> 6;
    const int n0  = blockIdx.x * 64;

    // staging: thread covers row tid>>2, k-chunk (tid&3)*8 within each 32-wide unit
    const int sr  = tid >> 2;
    const int kc  = tid & 3;
    const int rts = sr >> 4, srr = sr & 15;
    int dls[3];
    #pragma unroll
    for (int u = 0; u < 3; u++)
        dls[u] = ((u*4 + rts)*64 + kc*16 + srr)*8;
    int crow = n0 + sr; if (crow > N-1) crow = N-1;
    const float* xrow = x + (size_t)crow*IN_DIM + kc*8;

    f32x4 acc[4][4];
    #pragma unroll
    for (int i = 0; i < 4; i++)
        #pragma unroll
        for (int rt = 0; rt < 4; rt++)
            acc[i][rt] = (f32x4){0.f, 0.f, 0.f, 0.f};

    float4 rx[6];
    uint4 wcur[4], wnxt[4];

    // prologue: stage 0 (k 0..95), W unit 0
    #pragma unroll
    for (int u = 0; u < 3; u++){
        rx[2*u]   = *(const float4*)(xrow + u*32);
        rx[2*u+1] = *(const float4*)(xrow + u*32 + 4);
    }
    #pragma unroll
    for (int u = 0; u < 3; u++){
        uint4 pk;
        pk.x = pack2(rx[2*u].x,   rx[2*u].y);   pk.y = pack2(rx[2*u].z,   rx[2*u].w);
        pk.z = pack2(rx[2*u+1].x, rx[2*u+1].y); pk.w = pack2(rx[2*u+1].z, rx[2*u+1].w);
        *(uint4*)&Af[0][dls[u]] = pk;
    }
    {
        const unsigned short* p = Wf + ((size_t)(w*4)*64 + l)*8;
        #pragma unroll
        for (int i = 0; i < 4; i++) wcur[i] = *(const uint4*)(p + (size_t)i*512);
    }
    __syncthreads();

    for (int s = 0; s < 4; ++s){
        if (s < 3){
            const float* src = xrow + (s+1)*96;
            #pragma unroll
            for (int u = 0; u < 3; u++){
                rx[2*u]   = *(const float4*)(src + u*32);
                rx[2*u+1] = *(const float4*)(src + u*32 + 4);
            }
        }
        #pragma unroll
        for (int u = 0; u < 3; u++){
            int ku = s*3 + u;
            if (ku < 11){
                const unsigned short* p = Wf + ((size_t)((ku+1)*16 + w*4)*64 + l)*8;
                #pragma unroll
                for (int i = 0; i < 4; i++) wnxt[i] = *(const uint4*)(p + (size_t)i*512);
            }
            bf16x8 af[4];
            #pragma unroll
            for (int rt = 0; rt < 4; rt++)
                af[rt] = __builtin_bit_cast(bf16x8, *(const uint4*)&Af[s&1][((u*4 + rt)*64 + l)*8]);
            #pragma unroll
            for (int i = 0; i < 4; i++){
                bf16x8 bw = __builtin_bit_cast(bf16x8, wcur[i]);
                #pragma unroll
                for (int rt = 0; rt < 4; rt++)
                    acc[i][rt] = __builtin_amdgcn_mfma_f32_16x16x32_bf16(bw, af[rt], acc[i][rt], 0, 0, 0);
            }
            if (ku < 11){
                #pragma unroll
                for (int i = 0; i < 4; i++) wcur[i] = wnxt[i];
            }
        }
        if (s < 3){
            #pragma unroll
            for (int u = 0; u < 3; u++){
                uint4 pk;
                pk.x = pack2(rx[2*u].x,   rx[2*u].y);   pk.y = pack2(rx[2*u].z,   rx[2*u].w);
                pk.z = pack2(rx[2*u+1].x, rx[2*u+1].y); pk.w = pack2(rx[2*u+1].z, rx[2*u+1].w);
                *(uint4*)&Af[(s+1)&1][dls[u]] = pk;
            }
            __syncthreads();
        }
    }

    const int g = l >> 4;
    float4 cvv[4], av[4], dv[4];
    #pragma unroll
    for (int i = 0; i < 4; i++){
        int cl = i*16 + g*4;
        cvv[i] = *(const float4*)&c1v[w*64 + cl];
        av[i]  = *(const float4*)&as1[w*64 + cl];
        dv[i]  = *(const float4*)&ad1[w*64 + cl];
    }
    #pragma unroll
    for (int rt = 0; rt < 4; rt++){
        int node = n0 + rt*16 + (l & 15);
        bool ok = node < N;
        float ps = 0.f, pd = 0.f;
        #pragma unroll
        for (int i = 0; i < 4; i++){
            float h0 = acc[i][rt][0] + cvv[i].x;
            float h1v = acc[i][rt][1] + cvv[i].y;
            float h2v = acc[i][rt][2] + cvv[i].z;
            float h3v = acc[i][rt][3] + cvv[i].w;
            ps += h0*av[i].x + h1v*av[i].y + h2v*av[i].z + h3v*av[i].w;
            pd += h0*dv[i].x + h1v*dv[i].y + h2v*dv[i].z + h3v*dv[i].w;
            if (ok){
                ushort4 o = make_ushort4(f2bf(h0), f2bf(h1v), f2bf(h2v), f2bf(h3v));
                *(ushort4*)&h1[(size_t)node*C1 + w*64 + i*16 + g*4] = o;
            }
        }
        ps += __shfl_xor(ps, 16, 64); ps += __shfl_xor(ps, 32, 64);
        pd += __shfl_xor(pd, 16, 64); pd += __shfl_xor(pd, 32, 64);
        if (ok && g == 0){
            als[(size_t)node*4 + w] = ps;
            ald[(size_t)node*4 + w] = pd;
        }
    }
}

// ---------------- GEMM2 (MFMA): h2 = x2 @ W2 + fused al2 epilogue ----------------
// 64 rows x 128 cols, 4 waves: wc = w&1 (head), wr = w>>1 (32-row half); acc[4][2]=32 AGPR
__global__ __launch_bounds__(256) void k_gemm2_mfma(const unsigned short* __restrict__ x2,
        const unsigned short* __restrict__ Wf,
        const float* __restrict__ as2, const float* __restrict__ ad2,
        unsigned short* __restrict__ h2, float* __restrict__ als, float* __restrict__ ald, int N)
{
    __shared__ unsigned short Af[2][4*64*8];   // 2 x 4KB
    const int tid = threadIdx.x;
    const int l   = tid & 63;
    const int w   = tid >> 6;
    const int wr  = w >> 1, wc = w & 1;
    const int n0  = blockIdx.x * 64;

    const int sr  = tid >> 2;
    const int kc  = tid & 3;
    const int d0  = ((sr >> 4)*64 + kc*16 + (sr & 15))*8;
    int crow = n0 + sr; if (crow > N-1) crow = N-1;
    const unsigned short* xrow = x2 + (size_t)crow*C1 + kc*8;

    f32x4 acc[4][2];
    #pragma unroll
    for (int i = 0; i < 4; i++)
        #pragma unroll
        for (int rt = 0; rt < 2; rt++)
            acc[i][rt] = (f32x4){0.f, 0.f, 0.f, 0.f};

    uint4 p0, wcur[4], wnxt[4];
    p0 = *(const uint4*)(xrow);
    *(uint4*)&Af[0][d0] = p0;
    {
        const unsigned short* p = Wf + ((size_t)(wc*4)*64 + l)*8;
        #pragma unroll
        for (int i = 0; i < 4; i++) wcur[i] = *(const uint4*)(p + (size_t)i*512);
    }
    __syncthreads();

    for (int s = 0; s < 8; ++s){
        if (s < 7){
            p0 = *(const uint4*)(xrow + (s+1)*32);
            const unsigned short* p = Wf + ((size_t)((s+1)*8 + wc*4)*64 + l)*8;
            #pragma unroll
            for (int i = 0; i < 4; i++) wnxt[i] = *(const uint4*)(p + (size_t)i*512);
        }
        bf16x8 af[2];
        #pragma unroll
        for (int rt = 0; rt < 2; rt++)
            af[rt] = __builtin_bit_cast(bf16x8, *(const uint4*)&Af[s&1][((wr*2 + rt)*64 + l)*8]);
        #pragma unroll
        for (int i = 0; i < 4; i++){
            bf16x8 bw = __builtin_bit_cast(bf16x8, wcur[i]);
            #pragma unroll
            for (int rt = 0; rt < 2; rt++)
                acc[i][rt] = __builtin_amdgcn_mfma_f32_16x16x32_bf16(bw, af[rt], acc[i][rt], 0, 0, 0);
        }
        if (s < 7){
            *(uint4*)&Af[(s+1)&1][d0] = p0;
            __syncthreads();
            #pragma unroll
            for (int i = 0; i < 4; i++) wcur[i] = wnxt[i];
        }
    }

    const int g = l >> 4;
    float4 av[4], dv[4];
    #pragma unroll
    for (int i = 0; i < 4; i++){
        int cl = i*16 + g*4;
        av[i] = *(const float4*)&as2[wc*64 + cl];
        dv[i] = *(const float4*)&ad2[wc*64 + cl];
    }
    #pragma unroll
    for (int rt = 0; rt < 2; rt++){
        int node = n0 + wr*32 + rt*16 + (l & 15);
        bool ok = node < N;
        float ps = 0.f, pd = 0.f;
        #pragma unroll
        for (int i = 0; i < 4; i++){
            float h0 = acc[i][rt][0], h1v = acc[i][rt][1];
            float h2v = acc[i][rt][2], h3v = acc[i][rt][3];
            ps += h0*av[i].x + h1v*av[i].y + h2v*av[i].z + h3v*av[i].w;
            pd += h0*dv[i].x + h1v*dv[i].y + h2v*dv[i].z + h3v*dv[i].w;
            if (ok){
                ushort4 o = make_ushort4(f2bf(h0), f2bf(h1v), f2bf(h2v), f2bf(h3v));
                *(ushort4*)&h2[(size_t)node*C2 + wc*64 + i*16 + g*4] = o;
            }
        }
        ps += __shfl_xor(ps, 16, 64); ps += __shfl_xor(ps, 32, 64);
        pd += __shfl_xor(pd, 16, 64); pd += __shfl_xor(pd, 32, 64);
        if (ok && g == 0){
            als[(size_t)node*2 + wc] = ps;
            ald[(size_t)node*2 + wc] = pd;
        }
    }
}

// ---------------- A: edge-parallel logits e = leaky(als[src]+ald[dst]) ----------------
template<int H>
__global__ __launch_bounds__(256) void k_elogit(const int* __restrict__ colx,
        const int* __restrict__ dstx, const float* __restrict__ als,
        const float* __restrict__ ald, float* __restrict__ ep, int E)
{
    int i = blockIdx.x*256 + threadIdx.x;
    if (i >= E) return;
    int s = colx[i], d = dstx[i];
    if constexpr (H == 4){
        float4 a = *(const float4*)&als[(size_t)s*4];
        float4 b = *(const float4*)&ald[(size_t)d*4];
        float4 e;
        e.x = a.x + b.x; e.x = fmaxf(e.x, 0.2f*e.x);
        e.y = a.y + b.y; e.y = fmaxf(e.y, 0.2f*e.y);
        e.z = a.z + b.z; e.z = fmaxf(e.z, 0.2f*e.z);
        e.w = a.w + b.w; e.w = fmaxf(e.w, 0.2f*e.w);
        *(float4*)&ep[(size_t)i*4] = e;
    } else {
        float2 a = *(const float2*)&als[(size_t)s*2];
        float2 b = *(const float2*)&ald[(size_t)d*2];
        float2 e;
        e.x = a.x + b.x; e.x = fmaxf(e.x, 0.2f*e.x);
        e.y = a.y + b.y; e.y = fmaxf(e.y, 0.2f*e.y);
        *(float2*)&ep[(size_t)i*2] = e;
    }
}

// ---------------- B: thread per (node,head) segment softmax; ep <- p (in place) -------
template<int H>
__global__ __launch_bounds__(256) void k_segsm(const int* __restrict__ rowptr,
        const float* __restrict__ als, const float* __restrict__ ald,
        float* __restrict__ ep, float* __restrict__ den, float* __restrict__ pSelf, int NH)
{
    int t = blockIdx.x*256 + threadIdx.x;
    if (t >= NH) return;
    int node = t / H;
    int head = t - node*H;
    int base = rowptr[node];
    int cnt  = rowptr[node+1] - base;
    float es = als[t] + ald[t];
    es = fmaxf(es, 0.2f*es);
    float m = es;
    for (int j = 0; j < cnt; j++)
        m = fmaxf(m, ep[(size_t)(base + j)*H + head]);
    float ps = __expf(es - m);
    float dn = ps;
    for (int j = 0; j < cnt; j++){
        size_t idx = (size_t)(base + j)*H + head;
        float p = __expf(ep[idx] - m);
        ep[idx] = p;
        dn += p;
    }
    den[t]   = dn;
    pSelf[t] = ps;
}

// ---------------- C: wave-per-node weighted gather-sum (no softmax in loop) ----------
template<int H, int CPL, int LAYER>
__global__ __launch_bounds__(256) void k_gat(const unsigned short* __restrict__ hlin,
        const float* __restrict__ ep, const float* __restrict__ den, const float* __restrict__ pSelf,
        const int* __restrict__ rowptr, const int* __restrict__ colx,
        const float* __restrict__ bias, const float* __restrict__ gate,
        unsigned short* __restrict__ out_bf, float* __restrict__ out_f, int N)
{
    constexpr int C = H*64;
    constexpr uint32 RB = C*2;               // bf16 row bytes
    int lane = threadIdx.x & 63, wid = threadIdx.x >> 6;
    int n = blockIdx.x*4 + wid;
    if (n >= N) return;
    const int c0 = lane*CPL;
    const int head = c0 >> 6;
    const int base = rowptr[n];
    const int cnt  = rowptr[n+1] - base;
    const char* hbase = (const char*)hlin + (uint32)c0*2;

    float acc[CPL];
    {
        float psf = pSelf[(uint32)n*H + head];
        if constexpr (CPL == 4){
            ushort4 v = *(const ushort4*)(hbase + (size_t)(uint32)n*RB);
            acc[0] = psf*bf2f(v.x); acc[1] = psf*bf2f(v.y);
            acc[2] = psf*bf2f(v.z); acc[3] = psf*bf2f(v.w);
        } else {
            uint32 v = *(const uint32*)(hbase + (size_t)(uint32)n*RB);
            acc[0] = psf*bf2f((unsigned short)(v & 0xffff));
            acc[1] = psf*bf2f((unsigned short)(v >> 16));
        }
    }
    for (int i = 0; i < cnt; i += 4){
        int idx[4], sk[4];
        #pragma unroll
        for (int k = 0; k < 4; k++){
            int ii = i + k; if (ii > cnt-1) ii = cnt-1;
            idx[k] = base + ii;
        }
        #pragma unroll
        for (int k = 0; k < 4; k++) sk[k] = colx[idx[k]];
        float pk[4];
        #pragma unroll
        for (int k = 0; k < 4; k++){
            float pv = ep[(size_t)(uint32)idx[k]*H + head];   // position-indexed: no colx dep
            pk[k] = (i + k < cnt) ? pv : 0.f;
        }
        if constexpr (CPL == 4){
            ushort4 h4[4];
            #pragma unroll
            for (int k = 0; k < 4; k++) h4[k] = *(const ushort4*)(hbase + (size_t)(uint32)sk[k]*RB);
            #pragma unroll
            for (int k = 0; k < 4; k++){
                acc[0] += pk[k]*bf2f(h4[k].x);
                acc[1] += pk[k]*bf2f(h4[k].y);
                acc[2] += pk[k]*bf2f(h4[k].z);
                acc[3] += pk[k]*bf2f(h4[k].w);
            }
        } else {
            uint32 h2v[4];
            #pragma unroll
            for (int k = 0; k < 4; k++) h2v[k] = *(const uint32*)(hbase + (size_t)(uint32)sk[k]*RB);
            #pragma unroll
            for (int k = 0; k < 4; k++){
                acc[0] += pk[k]*bf2f((unsigned short)(h2v[k] & 0xffff));
                acc[1] += pk[k]*bf2f((unsigned short)(h2v[k] >> 16));
            }
        }
    }

    float inv = 1.f/(den[(uint32)n*H + head] + 1e-16f);
    if constexpr (LAYER == 1){
        unsigned short o[CPL];
        #pragma unroll
        for (int j = 0; j < CPL; j++){
            float r = acc[j]*inv + bias[c0 + j];
            r = (r > 0.f) ? r : (__expf(r) - 1.f);   // elu
            o[j] = f2bf(r);
        }
        if constexpr (CPL == 4){
            ushort4 ov; ov.x = o[0]; ov.y = o[1]; ov.z = o[2]; ov.w = o[3];
            *(ushort4*)&out_bf[(size_t)n*C + c0] = ov;
        }
    } else {
        float o[CPL];
        #pragma unroll
        for (int j = 0; j < CPL; j++){
            float r = acc[j]*inv + bias[c0 + j];
            r = (r > 0.f) ? r : (__expf(r) - 1.f);   // elu
            o[j] = r*gate[(c0 + j) & 63];
        }
        if constexpr (CPL == 2){
            *(float2*)&out_f[(size_t)n*C + c0] = make_float2(o[0], o[1]);
        }
    }
}

// ---------------- attn MLP via MFMA: attn = sigmoid(relu(outh@aw1+ab1)@aw2+ab2) -------
__global__ __launch_bounds__(256) void k_attn_mfma(const float* __restrict__ outh,
        const unsigned short* __restrict__ Wfa, const float* __restrict__ ab1,
        const float* __restrict__ aw2, const float* __restrict__ ab2,
        float* __restrict__ attn, int N)
{
    __shared__ unsigned short Af[4*8*64*8];   // 32 KB: [kstep s][rowtile rt][lane][8]
    const int tid = threadIdx.x;
    const int l   = tid & 63;
    const int w   = tid >> 6;
    const int n0  = blockIdx.x * 128;

    const int r  = tid >> 1;
    const int kh = tid & 1;
    const int rt8 = r >> 4, rr = r & 15;
    int crow = n0 + r; if (crow > N-1) crow = N-1;
    const float* src = outh + (size_t)crow*C2 + kh*16;
    #pragma unroll
    for (int s = 0; s < 4; s++){
        float4 a = *(const float4*)(src + s*32 + 0);
        float4 b = *(const float4*)(src + s*32 + 4);
        float4 c = *(const float4*)(src + s*32 + 8);
        float4 d = *(const float4*)(src + s*32 + 12);
        uint4 u0, u1;
        u0.x = pack2(a.x, a.y); u0.y = pack2(a.z, a.w);
        u0.z = pack2(b.x, b.y); u0.w = pack2(b.z, b.w);
        u1.x = pack2(c.x, c.y); u1.y = pack2(c.z, c.w);
        u1.z = pack2(d.x, d.y); u1.w = pack2(d.z, d.w);
        int d0 = ((s*8 + rt8)*64 + (kh*2)*16 + rr)*8;
        *(uint4*)&Af[d0]       = u0;
        *(uint4*)&Af[d0 + 128] = u1;
    }
    __syncthreads();

    f32x4 acc[4][2];
    #pragma unroll
    for (int i = 0; i < 4; i++)
        #pragma unroll
        for (int rt = 0; rt < 2; rt++)
            acc[i][rt] = (f32x4){0.f, 0.f, 0.f, 0.f};

    #pragma unroll
    for (int s = 0; s < 4; s++){
        bf16x8 af[2];
        #pragma unroll
        for (int rt = 0; rt < 2; rt++)
            af[rt] = __builtin_bit_cast(bf16x8, *(const uint4*)&Af[((s*8 + w*2 + rt)*64 + l)*8]);
        #pragma unroll
        for (int i = 0; i < 4; i++){
            bf16x8 bw = __builtin_bit_cast(bf16x8, *(const uint4*)&Wfa[((size_t)(s*4 + i)*64 + l)*8]);
            #pragma unroll
            for (int rt = 0; rt < 2; rt++)
                acc[i][rt] = __builtin_amdgcn_mfma_f32_16x16x32_bf16(bw, af[rt], acc[i][rt], 0, 0, 0);
        }
    }

    const int g = l >> 4;
    float4 abv[4], awv[4];
    #pragma unroll
    for (int i = 0; i < 4; i++){
        abv[i] = *(const float4*)&ab1[i*16 + g*4];
        awv[i] = *(const float4*)&aw2[i*16 + g*4];
    }
    float b2v = ab2[0];
    #pragma unroll
    for (int rt = 0; rt < 2; rt++){
        int node = n0 + (w*2 + rt)*16 + (l & 15);
        float part = 0.f;
        #pragma unroll
        for (int i = 0; i < 4; i++){
            float v0 = fmaxf(acc[i][rt][0] + abv[i].x, 0.f);
            float v1 = fmaxf(acc[i][rt][1] + abv[i].y, 0.f);
            float v2 = fmaxf(acc[i][rt][2] + abv[i].z, 0.f);
            float v3 = fmaxf(acc[i][rt][3] + abv[i].w, 0.f);
            part += v0*awv[i].x + v1*awv[i].y + v2*awv[i].z + v3*awv[i].w;
        }
        part += __shfl_xor(part, 16, 64);
        part += __shfl_xor(part, 32, 64);
        if (g == 0 && node < N)
            attn[node] = 1.f/(1.f + __expf(-(part + b2v)));
    }
}

extern "C" void kernel_launch(void* const* d_in, const int* in_sizes, int n_in,
                              void* d_out, int out_size, void* d_ws, size_t ws_size,
                              hipStream_t stream)
{
    const float* x    = (const float*)d_in[0];
    const int*   ei   = (const int*)  d_in[1];
    const float* pad  = (const float*)d_in[2];
    const float* W1   = (const float*)d_in[3];
    const float* as1  = (const float*)d_in[4];
    const float* ad1  = (const float*)d_in[5];
    const float* b1   = (const float*)d_in[6];
    const float* W2   = (const float*)d_in[7];
    const float* as2  = (const float*)d_in[8];
    const float* ad2  = (const float*)d_in[9];
    const float* b2   = (const float*)d_in[10];
    const float* aw1  = (const float*)d_in[11];
    const float* ab1  = (const float*)d_in[12];
    const float* aw2  = (const float*)d_in[13];
    const float* ab2  = (const float*)d_in[14];
    const float* gw   = (const float*)d_in[15];
    const float* gb   = (const float*)d_in[16];

    const int N = in_sizes[0] / IN_DIM;
    const int E = in_sizes[1] / 2;

    float* outh    = (float*)d_out;
    float* outattn = outh + (size_t)N*C2;

    char* w = (char*)d_ws;
    auto alloc = [&](size_t bytes)->char*{
        char* p = w;
        w += (bytes + 255) & ~(size_t)255;
        return p;
    };
    unsigned short* h1  = (unsigned short*)alloc((size_t)N*C1*2);
    unsigned short* x2  = (unsigned short*)alloc((size_t)N*C1*2);
    unsigned short* h2  = (unsigned short*)alloc((size_t)N*C2*2);
    float* als1 = (float*)alloc((size_t)N*4*4);
    float* ald1 = (float*)alloc((size_t)N*4*4);
    float* als2 = (float*)alloc((size_t)N*2*4);
    float* ald2 = (float*)alloc((size_t)N*2*4);
    int* deg    = (int*)alloc((size_t)N*4);
    int* cur    = (int*)alloc((size_t)N*4);
    int* rowptr = (int*)alloc((size_t)(N+1)*4);
    int* colx   = (int*)alloc((size_t)E*4);
    int* dstx   = (int*)alloc((size_t)E*4);
    int* part   = (int*)alloc(512*4);
    unsigned short* Wf1 = (unsigned short*)alloc((size_t)12*16*64*8*2);
    unsigned short* Wf2 = (unsigned short*)alloc((size_t)8*8*64*8*2);
    unsigned short* Wfa = (unsigned short*)alloc((size_t)4*4*64*8*2);
    float* c1v  = (float*)alloc(C1*4);
    float* gate = (float*)alloc(HID*4);

    // Lifetime-based aliases (no new footprint):
    float* ep1    = (float*)h2;                                   // E*4 floats
    float* den1   = (float*)((char*)h2 + (size_t)E*16);           // N*4 floats
    float* pSelf1 = (float*)((char*)h2 + (size_t)E*16 + (size_t)N*16);
    float* ep2    = (float*)x2;                                   // E*2 floats
    float* den2   = (float*)((char*)x2 + (size_t)E*8);            // N*2 floats
    float* pSelf2 = (float*)((char*)x2 + (size_t)E*8 + (size_t)N*8);

    const int nbN = (N + 255)/256;
    const int nbE = (E + 255)/256;
    const int nbW = (N + 3)/4;        // wave-per-node kernels
    const int nbG = (N + 63)/64;      // gemm row blocks (64-row tiles)
    const int nbA = (N + 127)/128;    // attn-MLP row blocks

    // weight swizzles + constants (independent of CSR)
    k_cvtW <<<(192+3)/4, 256, 0, stream>>>(W1, Wf1, C1, 16, 192);
    k_cvtW <<<(64+3)/4,  256, 0, stream>>>(W2, Wf2, C2, 8, 64);
    k_cvtW <<<(16+3)/4,  256, 0, stream>>>(aw1, Wfa, HID, 4, 16);
    k_prep <<<1, 256, 0, stream>>>(W1, pad, gw, gb, c1v, gate);

    // CSR by destination
    k_zero   <<<nbN, 256, 0, stream>>>(deg, cur, N);
    k_hist   <<<nbE, 256, 0, stream>>>(ei, deg, E);
    k_scan1  <<<nbN, 256, 0, stream>>>(deg, rowptr, part, N);
    k_scan2  <<<1, 512, 0, stream>>>(part, nbN);
    k_scan3  <<<nbN, 256, 0, stream>>>(rowptr, part, N, E);
    k_scatter<<<nbE, 256, 0, stream>>>(ei, rowptr, cur, colx, dstx, E);

    // ---- layer 1 ----
    k_gemm1_mfma<<<nbG, 256, 0, stream>>>(x, Wf1, c1v, as1, ad1, h1, als1, ald1, N);
    k_elogit<4><<<nbE, 256, 0, stream>>>(colx, dstx, als1, ald1, ep1, E);
    k_segsm<4> <<<(N*4 + 255)/256, 256, 0, stream>>>(rowptr, als1, ald1, ep1, den1, pSelf1, N*4);
    k_gat<4,4,1><<<nbW, 256, 0, stream>>>(h1, ep1, den1, pSelf1, rowptr, colx, b1,
                                          nullptr, x2, nullptr, N);

    // ---- layer 2 ----
    k_gemm2_mfma<<<nbG, 256, 0, stream>>>(x2, Wf2, as2, ad2, h2, als2, ald2, N);
    k_elogit<2><<<nbE, 256, 0, stream>>>(colx, dstx, als2, ald2, ep2, E);
    k_segsm<2> <<<(N*2 + 255)/256, 256, 0, stream>>>(rowptr, als2, ald2, ep2, den2, pSelf2, N*2);
    k_gat<2,2,2><<<nbW, 256, 0, stream>>>(h2, ep2, den2, pSelf2, rowptr, colx, b2,
                                          gate, nullptr, outh, N);

    // ---- attention-score MLP (MFMA) ----
    k_attn_mfma<<<nbA, 256, 0, stream>>>(outh, Wfa, ab1, aw2, ab2, outattn, N);
}